// Round 1
// baseline (538.769 us; speedup 1.0000x reference)
//
#include <hip/hip_runtime.h>
#include <hip/hip_bf16.h>

#define BB 2
#define CC 512
#define HH 14
#define WW 14
#define PP 196
#define NSEQ 8
#define NSLICE 8                 // worker WGs per row (64 ch each)
#define NWORK (14 * NSLICE)      // 112
#define FW 16                    // words per counter line (64B)
#define NZERO (2 * PP * FW + PP * 16)  // ucnt + hcnt + dsAcc (f32 zeros)

// counters: ucnt[cell*FW] counts slice publishes (8 = E/TL/ds ready)
//           hcnt[cell*FW] counts bulk-window wave publishes (8 = h_bulk ready)

// ---------------------------------------------------------------------------
// prep: gemm_a (224 WGs) + transpose_wh (256 WGs) + counter/dsAcc zero (1 WG)
// ---------------------------------------------------------------------------
__global__ __launch_bounds__(256) void prep(
    const float* __restrict__ Wx, const float* __restrict__ X,
    const float* __restrict__ b_in, const float* __restrict__ Wh,
    float* __restrict__ A, float* __restrict__ WhT,
    unsigned* __restrict__ cnts /* ucnt, hcnt, dsAcc contiguous */) {
    __shared__ float Ws[32][33], Xs[32][33];
    int bid = blockIdx.x;
    int t = threadIdx.x;
    if (bid < 224) {
        int z = bid / 112, rem = bid % 112;
        int c0 = (rem % 16) * 32, p0 = (rem / 16) * 32;
        int tx = t % 32, ty = t / 32;
        int pl = (t % 16) * 2, cl = (t / 16) * 2;
        float acc[2][2] = {{0.f,0.f},{0.f,0.f}};
        for (int k0 = 0; k0 < CC; k0 += 32) {
            #pragma unroll
            for (int r = 0; r < 4; ++r)
                Ws[ty + 8*r][tx] = Wx[(size_t)(c0 + ty + 8*r) * CC + k0 + tx];
            #pragma unroll
            for (int r = 0; r < 4; ++r) {
                int p = p0 + tx, k = k0 + ty + 8*r;
                Xs[ty + 8*r][tx] = (p < PP) ? X[((size_t)z * CC + k) * PP + p] : 0.f;
            }
            __syncthreads();
            #pragma unroll
            for (int k = 0; k < 32; ++k) {
                float w0 = Ws[cl][k], w1 = Ws[cl+1][k];
                float x0 = Xs[k][pl], x1 = Xs[k][pl+1];
                acc[0][0] += w0*x0; acc[0][1] += w0*x1;
                acc[1][0] += w1*x0; acc[1][1] += w1*x1;
            }
            __syncthreads();
        }
        #pragma unroll
        for (int i = 0; i < 2; ++i)
            #pragma unroll
            for (int j = 0; j < 2; ++j) {
                int c = c0 + cl + i, p = p0 + pl + j;
                if (p < PP) A[((size_t)z * PP + p) * CC + c] = acc[i][j] + b_in[c];
            }
    } else if (bid < 480) {
        int tid = bid - 224;
        int c0 = (tid % 16) * 32, k0 = (tid / 16) * 32;
        int tx = t % 32, ty = t / 32;
        #pragma unroll
        for (int r = 0; r < 4; ++r)
            Ws[ty + 8*r][tx] = Wh[(size_t)(c0 + ty + 8*r) * CC + k0 + tx];
        __syncthreads();
        #pragma unroll
        for (int r = 0; r < 4; ++r)
            WhT[(size_t)(k0 + ty + 8*r) * CC + c0 + tx] = Ws[tx][ty + 8*r];
    } else {
        for (int i = t; i < NZERO; i += 256) cnts[i] = 0u;
    }
}

// ---------------------------------------------------------------------------
// sync primitives
// ---------------------------------------------------------------------------
__device__ __forceinline__ unsigned flag_ld(const unsigned* f) {
    return __hip_atomic_load(f, __ATOMIC_RELAXED, __HIP_MEMORY_SCOPE_AGENT);
}
__device__ __forceinline__ float ldf_agent(const float* p) {
    return __hip_atomic_load(p, __ATOMIC_RELAXED, __HIP_MEMORY_SCOPE_AGENT);
}
__device__ __forceinline__ void store_wt(float* p, float v) {
    __hip_atomic_store(p, v, __ATOMIC_RELAXED, __HIP_MEMORY_SCOPE_AGENT);
}

// one window pixel for 8 channels (this wave's seq); E = exp(U) input
__device__ __forceinline__ void pix(const float4 E0, const float4 E1,
                                    const float* ar, const float* er, float* hacc) {
    float ee[8] = {E0.x,E0.y,E0.z,E0.w,E1.x,E1.y,E1.z,E1.w};
    float ds = 0.f, tl[8];
    #pragma unroll
    for (int j = 0; j < 8; ++j) {
        float sv = ar[j] + __logf(ee[j]);
        float pv = er[j] * ee[j];
        ds += fmaxf(pv, 1.0f);
        tl[j] = fmaxf(sv, 0.0f) * pv;
    }
    #pragma unroll
    for (int off = 32; off; off >>= 1) ds += __shfl_xor(ds, off, 64);
    float rd = 1.0f / ds;
    #pragma unroll
    for (int j = 0; j < 8; ++j) hacc[j] += tl[j] * rd;
}

// process n pixels at rowp + y*CC, 4-deep pipelined plain loads
__device__ __forceinline__ void proc_row(const float* __restrict__ rowp, int n,
                                         const float* ar, const float* er, float* hacc) {
    float4 cur[4][2];
    int y = 0, curn = (n < 4) ? n : 4;
    #pragma unroll
    for (int i = 0; i < 4; ++i) if (i < curn) {
        cur[i][0] = *(const float4*)(rowp + (size_t)i * CC);
        cur[i][1] = *(const float4*)(rowp + (size_t)i * CC + 256);
    }
    while (true) {
        int yn = y + curn;
        int rem = n - yn;
        int nextn = (rem < 4) ? rem : 4;
        float4 nxt[4][2];
        #pragma unroll
        for (int i = 0; i < 4; ++i) if (i < nextn) {
            nxt[i][0] = *(const float4*)(rowp + (size_t)(yn + i) * CC);
            nxt[i][1] = *(const float4*)(rowp + (size_t)(yn + i) * CC + 256);
        }
        #pragma unroll
        for (int i = 0; i < 4; ++i) if (i < curn)
            pix(cur[i][0], cur[i][1], ar, er, hacc);
        if (nextn <= 0) break;
        #pragma unroll
        for (int i = 0; i < 4; ++i) if (i < nextn) {
            cur[i][0] = nxt[i][0]; cur[i][1] = nxt[i][1];
        }
        curn = nextn; y = yn;
    }
}

// ---------------------------------------------------------------------------
// One kernel, two roles:
//   blockIdx 0..111   : row workers (row=bid>>3, 64-ch slice).
//     NEW: producer-side tail precompute. At publish, each slice computes for
//     its South/East consumer cells: tl = max(a_cons+U,0)*exp(a_cons)*E and
//     per-slice denominator partials (f32 global atomics into dsAcc). The
//     consumer just does h = hb + tlN*rcp(dsN) + tlW*rcp(dsW) -- no logs,
//     no 96-shfl reduce, no red/dsf barrier dance.
//     NEW: matvec k-split per wave (wave w owns k in [64w,64w+64)), fragments
//     read as uniform-address ds_read_b128 from stride-8 hT8, partials to
//     per-wave LDS buffer (plain overwrite), publish sums 8 -- no 160-shfl.
//   blockIdx 112..307 : per-cell bulk WGs -- unchanged.
// ---------------------------------------------------------------------------
__global__ __launch_bounds__(512, 4) void rnn_dataflow(
    const float* __restrict__ A, const float* __restrict__ WhT,
    float* __restrict__ E, float* __restrict__ h_bulk,
    float* __restrict__ h_t, float* __restrict__ TLN,
    float* __restrict__ TLW, float* __restrict__ dsAcc,
    unsigned* __restrict__ ucnt, unsigned* __restrict__ hcnt) {
    __shared__ __align__(16) float hT8[CC * 8];   // full h [k][s], stride 8
    __shared__ __align__(16) float up[8 * 576];   // matvec partials [wave][c*9+s]
    __shared__ unsigned mbox;                     // bulk WG: ready-rows bitmap
    int bid = blockIdx.x;
    int t = threadIdx.x;
    int lane = t & 63, wv = t >> 6;

    if (bid < NWORK) {
        // ================= row worker =================
        int px = bid >> 3, w = bid & 7;
        int ch = w * 64 + lane;                   // this thread's publish channel
        int m = wv >> 1, b = wv & 1;              // seq decode (s = wv)
        float wreg2[64];                          // WhT[64wv+kk][ch]
        #pragma unroll
        for (int kk = 0; kk < 64; ++kk)
            wreg2[kk] = WhT[(size_t)(wv * 64 + kk) * CC + ch];
        __builtin_amdgcn_s_setprio(1);

        for (int py = 0; py < WW; ++py) {
            int cell = px * WW + py;
            int cellN = cell - WW, cellW = cell - 1;

            // prefetch consumer-cell a values (overlaps the poll)
            float aSr = 0.f, aWr = 0.f;
            if (px < HH - 1) {
                int fi = (m & 2) ? (HH - 2 - px) : (px + 1);
                int fj = (m & 1) ? (WW - 1 - py) : py;
                aSr = A[((size_t)b * PP + fi * WW + fj) * CC + ch];
            }
            if (py < WW - 1) {
                int fi = (m & 2) ? (HH - 1 - px) : px;
                int fj = (m & 1) ? (WW - 2 - py) : (py + 1);
                aWr = A[((size_t)b * PP + fi * WW + fj) * CC + ch];
            }

            // merged poll: ONE lane per counter (lanes 0:N, 1:W, 2:h_bulk)
            if (wv == 0) {
                while (true) {
                    unsigned ok = 1u;
                    if (lane == 0)      { if (px > 0) ok = (flag_ld(ucnt + (size_t)cellN * FW) >= 8u); }
                    else if (lane == 1) { if (py > 0) ok = (flag_ld(ucnt + (size_t)cellW * FW) >= 8u); }
                    else if (lane == 2) ok = (flag_ld(hcnt + (size_t)cell * FW) >= 8u);
                    if (__ballot(ok != 0u) == ~0ull) break;
                    __builtin_amdgcn_s_sleep(1);
                }
            }
            __syncthreads();
            asm volatile("" ::: "memory");

            // stage: h_bulk + producer-precomputed tails (channel = t)
            float hb[8];
            #pragma unroll
            for (int s = 0; s < 8; ++s)
                hb[s] = h_bulk[((size_t)cell * NSEQ + s) * CC + t];
            float tn[8] = {}, tw[8] = {}, rdN[8] = {}, rdW[8] = {};
            if (px > 0) {
                #pragma unroll
                for (int s = 0; s < 8; ++s)
                    tn[s] = ldf_agent(&TLN[((size_t)cell * NSEQ + s) * CC + t]);
                #pragma unroll
                for (int s = 0; s < 8; ++s)
                    rdN[s] = __builtin_amdgcn_rcpf(ldf_agent(&dsAcc[(size_t)cell * 16 + s]));
            }
            if (py > 0) {
                #pragma unroll
                for (int s = 0; s < 8; ++s)
                    tw[s] = ldf_agent(&TLW[((size_t)cell * NSEQ + s) * CC + t]);
                #pragma unroll
                for (int s = 0; s < 8; ++s)
                    rdW[s] = __builtin_amdgcn_rcpf(ldf_agent(&dsAcc[(size_t)cell * 16 + 8 + s]));
            }
            float hv[8];
            #pragma unroll
            for (int s = 0; s < 8; ++s) {
                float h = hb[s] + tn[s] * rdN[s] + tw[s] * rdW[s];
                hv[s] = h;
                if (w == 0) h_t[((size_t)cell * NSEQ + s) * CC + t] = h;  // for gemm_y
            }
            *(float4*)&hT8[t * 8]     = make_float4(hv[0], hv[1], hv[2], hv[3]);
            *(float4*)&hT8[t * 8 + 4] = make_float4(hv[4], hv[5], hv[6], hv[7]);
            __syncthreads();
            if (cell == PP - 1) break;           // (13,13): no U consumer

            // matvec: wave wv owns k in [64wv, 64wv+64); lane owns channel.
            // hT8 reads are wave-uniform b128 (LDS broadcast, conflict-free).
            float acc[8] = {0.f,0.f,0.f,0.f,0.f,0.f,0.f,0.f};
            const float* hp = hT8 + (wv << 9);
            #pragma unroll
            for (int kk = 0; kk < 64; ++kk) {
                float4 h0 = *(const float4*)(hp + kk * 8);
                float4 h1 = *(const float4*)(hp + kk * 8 + 4);
                float wvv = wreg2[kk];
                acc[0] += wvv * h0.x; acc[1] += wvv * h0.y;
                acc[2] += wvv * h0.z; acc[3] += wvv * h0.w;
                acc[4] += wvv * h1.x; acc[5] += wvv * h1.y;
                acc[6] += wvv * h1.z; acc[7] += wvv * h1.w;
            }
            #pragma unroll
            for (int s = 0; s < 8; ++s)
                up[wv * 576 + lane * 9 + s] = acc[s];   // full overwrite, no zeroing
            __syncthreads();

            // publish: U, E = exp(U), consumer tails + denominator partials
            {
                float U = up[lane * 9 + wv];
                #pragma unroll
                for (int w2 = 1; w2 < 8; ++w2) U += up[w2 * 576 + lane * 9 + wv];
                float Ev = __expf(U);
                store_wt(&E[((size_t)wv * PP + cell) * CC + ch], Ev);
                float pdS = 0.f, pdW = 0.f;
                if (px < HH - 1) {
                    float pv = __expf(aSr) * Ev;
                    store_wt(&TLN[((size_t)(cell + WW) * NSEQ + wv) * CC + ch],
                             fmaxf(aSr + U, 0.f) * pv);
                    pdS = fmaxf(pv, 1.f);
                }
                if (py < WW - 1) {
                    float pv = __expf(aWr) * Ev;
                    store_wt(&TLW[((size_t)(cell + 1) * NSEQ + wv) * CC + ch],
                             fmaxf(aWr + U, 0.f) * pv);
                    pdW = fmaxf(pv, 1.f);
                }
                #pragma unroll
                for (int off = 32; off; off >>= 1) {
                    pdS += __shfl_xor(pdS, off, 64);
                    pdW += __shfl_xor(pdW, off, 64);
                }
                if (lane == 0) {
                    if (px < HH - 1)
                        unsafeAtomicAdd(&dsAcc[(size_t)(cell + WW) * 16 + wv], pdS);
                    if (py < WW - 1)
                        unsafeAtomicAdd(&dsAcc[(size_t)(cell + 1) * 16 + 8 + wv], pdW);
                }
            }
            __syncthreads();     // all waves' stores/atomics drained (vmcnt 0 @ barrier)
            if (t == 0) atomicAdd(ucnt + (size_t)cell * FW, 1u);
        }
    } else {
        // ================= bulk window WG (self + slack>=2), off-path =======
        int cell = bid - NWORK;
        int px = cell / WW, py = cell % WW;
        int s = wv, m = s >> 1, b = s & 1;
        int fi = (m & 2) ? (HH-1-px) : px;
        int fj = (m & 1) ? (WW-1-py) : py;
        int cb = lane * 4;

        if (t == 0) mbox = 0u;
        __syncthreads();          // once, at WG start (long before deps ready)

        const float* acur = A + ((size_t)b * PP + fi * WW + fj) * CC;
        float4 a0 = *(const float4*)(acur + cb);
        float4 a1 = *(const float4*)(acur + cb + 256);
        float ar[8] = {a0.x,a0.y,a0.z,a0.w,a1.x,a1.y,a1.z,a1.w};
        float er[8];
        #pragma unroll
        for (int j = 0; j < 8; ++j) er[j] = __expf(ar[j]);
        float hacc[8] = {0.f,0.f,0.f,0.f,0.f,0.f,0.f,0.f};

        {   // self pixel first (needs no U at all): U=0 -> E=1
            float ds = 0.f, tl[8];
            #pragma unroll
            for (int j = 0; j < 8; ++j) {
                float pv = er[j];
                ds += fmaxf(pv, 1.0f);
                tl[j] = fmaxf(ar[j], 0.0f) * pv;
            }
            #pragma unroll
            for (int off = 32; off; off >>= 1) ds += __shfl_xor(ds, off, 64);
            float rd = 1.0f / ds;
            #pragma unroll
            for (int j = 0; j < 8; ++j) hacc[j] += tl[j] * rd;
        }

        const float* Eb = E + (size_t)s * PP * CC;
        // bulk rows: x<=px-2 -> y<=py ; x=px-1 -> y<=py-1 ; x=px -> y<=py-2
        unsigned pend = 0u;
        for (int x = 0; x <= px; ++x) {
            int yl = (x <= px-2) ? py : ((x == px-1) ? py-1 : py-2);
            if (yl >= 0) pend |= (1u << x);
        }
        if (wv == 0) {
            // sole fabric poller: lane r checks row r's tail counter
            unsigned done = 0u;
            while (pend) {
                bool rdy = true;
                if (lane <= px && (pend & (1u << lane))) {
                    int yl = (lane <= px-2) ? py : ((lane == px-1) ? py-1 : py-2);
                    rdy = flag_ld(ucnt + (size_t)(lane * WW + yl) * FW) >= 8u;
                }
                unsigned long long bal = __ballot(rdy);
                unsigned newly = 0u, rem2 = pend;
                while (rem2) {
                    int x = __ffs(rem2) - 1; rem2 &= rem2 - 1;
                    if ((bal >> x) & 1ull) newly |= 1u << x;
                }
                if (!newly) { __builtin_amdgcn_s_sleep(2); continue; }
                done |= newly;
                __hip_atomic_store(&mbox, done, __ATOMIC_RELAXED,
                                   __HIP_MEMORY_SCOPE_WORKGROUP);
                asm volatile("" ::: "memory");
                unsigned go = newly;
                while (go) {
                    int x = __ffs(go) - 1; go &= go - 1;
                    int yl = (x <= px-2) ? py : ((x == px-1) ? py-1 : py-2);
                    proc_row(Eb + (size_t)(x * WW) * CC + cb, yl + 1, ar, er, hacc);
                }
                pend &= ~newly;
            }
        } else {
            while (pend) {
                unsigned d = __hip_atomic_load(&mbox, __ATOMIC_RELAXED,
                                               __HIP_MEMORY_SCOPE_WORKGROUP);
                unsigned newly = d & pend;
                if (!newly) { __builtin_amdgcn_s_sleep(2); continue; }
                asm volatile("" ::: "memory");
                unsigned go = newly;
                while (go) {
                    int x = __ffs(go) - 1; go &= go - 1;
                    int yl = (x <= px-2) ? py : ((x == px-1) ? py-1 : py-2);
                    proc_row(Eb + (size_t)(x * WW) * CC + cb, yl + 1, ar, er, hacc);
                }
                pend &= ~newly;
            }
        }

        // per-wave publish h_bulk: contiguous WT stores + drain + counter
        float* hp = h_bulk + ((size_t)cell * NSEQ + s) * CC;
        #pragma unroll
        for (int j = 0; j < 4; ++j) {
            store_wt(hp + cb + j,       hacc[j]);
            store_wt(hp + cb + 256 + j, hacc[4 + j]);
        }
        __builtin_amdgcn_s_waitcnt(0);
        asm volatile("" ::: "memory");
        if (lane == 0) atomicAdd(hcnt + (size_t)cell * FW, 1u);
    }
}

// ---------------------------------------------------------------------------
// gemm_y: Y[b][p][c] = sum_k Wo[c][k] * (sum_m h_t[p][2m+b][k]) + 4*b_out[c]
// ---------------------------------------------------------------------------
__global__ __launch_bounds__(256) void gemm_y(
    const float* __restrict__ Wo, const float* __restrict__ h_t,
    const float* __restrict__ b_out, float* __restrict__ Y) {
    __shared__ float Ws[32][33], Hs[32][33];
    int b  = blockIdx.z;
    int c0 = blockIdx.x * 32, p0 = blockIdx.y * 32;
    int t  = threadIdx.x;
    int tx = t % 32, ty = t / 32;
    int pl = (t % 16) * 2, cl = (t / 16) * 2;
    float acc[2][2] = {{0.f,0.f},{0.f,0.f}};
    for (int k0 = 0; k0 < CC; k0 += 32) {
        #pragma unroll
        for (int r = 0; r < 4; ++r)
            Ws[ty + 8*r][tx] = Wo[(size_t)(c0 + ty + 8*r) * CC + k0 + tx];
        #pragma unroll
        for (int r = 0; r < 4; ++r) {
            int p = p0 + ty + 8*r;
            float v = 0.f;
            if (p < PP) {
                size_t base = (size_t)p * NSEQ * CC + k0 + tx;
                v = h_t[base + (size_t)(0 + b) * CC]
                  + h_t[base + (size_t)(2 + b) * CC]
                  + h_t[base + (size_t)(4 + b) * CC]
                  + h_t[base + (size_t)(6 + b) * CC];
            }
            Hs[tx][ty + 8*r] = v;
        }
        __syncthreads();
        #pragma unroll
        for (int k = 0; k < 32; ++k) {
            float w0 = Ws[cl][k], w1 = Ws[cl+1][k];
            float h0 = Hs[k][pl], h1 = Hs[k][pl+1];
            acc[0][0] += w0*h0; acc[0][1] += w0*h1;
            acc[1][0] += w1*h0; acc[1][1] += w1*h1;
        }
        __syncthreads();
    }
    #pragma unroll
    for (int i = 0; i < 2; ++i)
        #pragma unroll
        for (int j = 0; j < 2; ++j) {
            int cc = c0 + cl + i, p = p0 + pl + j;
            if (p < PP) Y[((size_t)b * PP + p) * CC + cc] = acc[i][j] + 4.0f * b_out[cc];
        }
}

// ---------------------------------------------------------------------------
// softmax over channels -> out[b][c][p]
// ---------------------------------------------------------------------------
__global__ __launch_bounds__(256) void softmax_out(
    const float* __restrict__ Y, float* __restrict__ out) {
    int wave = threadIdx.x >> 6, lane = threadIdx.x & 63;
    int idx = blockIdx.x * 4 + wave;
    if (idx >= BB * PP) return;
    int b = idx / PP, p = idx % PP;
    const float* y = Y + ((size_t)b * PP + p) * CC;
    float v[8];
    float mx = -3.4e38f;
    #pragma unroll
    for (int j = 0; j < 8; ++j) { v[j] = y[lane + 64*j]; mx = fmaxf(mx, v[j]); }
    #pragma unroll
    for (int off = 32; off; off >>= 1) mx = fmaxf(mx, __shfl_xor(mx, off, 64));
    float sum = 0.f;
    #pragma unroll
    for (int j = 0; j < 8; ++j) { v[j] = expf(v[j] - mx); sum += v[j]; }
    #pragma unroll
    for (int off = 32; off; off >>= 1) sum += __shfl_xor(sum, off, 64);
    float r = 1.0f / sum;
    #pragma unroll
    for (int j = 0; j < 8; ++j)
        out[((size_t)b * CC + lane + 64*j) * PP + p] = v[j] * r;
}

// ---------------------------------------------------------------------------
extern "C" void kernel_launch(void* const* d_in, const int* in_sizes, int n_in,
                              void* d_out, int out_size, void* d_ws, size_t ws_size,
                              hipStream_t stream) {
    const float* X     = (const float*)d_in[0];
    const float* Wx    = (const float*)d_in[1];
    const float* Wh    = (const float*)d_in[2];
    const float* b_in  = (const float*)d_in[3];
    const float* Wo    = (const float*)d_in[4];
    const float* b_out = (const float*)d_in[5];
    float* out = (float*)d_out;

    float* ws     = (float*)d_ws;
    float* WhT    = ws;                     // 262144
    float* A      = WhT    + 262144;        // 200704
    float* E      = A      + 200704;        // 802816  [s][cell][c] = exp(U)
    float* h_bulk = E      + 802816;        // 802816  [cell][s][c]
    float* h_t    = h_bulk + 802816;        // 802816  [cell][s][c] full h
    float* TLN    = h_t    + 802816;        // 802816  [cell][s][c] tail from North
    float* TLW    = TLN    + 802816;        // 802816  [cell][s][c] tail from West
    float* Y      = TLW    + 802816;        // 200704
    unsigned* ucnt = (unsigned*)(Y + 200704);       // PP*FW
    unsigned* hcnt = ucnt + PP * FW;                // PP*FW
    float* dsAcc   = (float*)(hcnt + PP * FW);      // PP*16: [cell][N:0-7|W:8-15]

    hipLaunchKernelGGL(prep, dim3(481), dim3(256), 0, stream,
                       Wx, X, b_in, Wh, A, WhT, ucnt);
    hipLaunchKernelGGL(rnn_dataflow, dim3(NWORK + PP), dim3(512), 0, stream,
                       A, WhT, E, h_bulk, h_t, TLN, TLW, dsAcc, ucnt, hcnt);
    hipLaunchKernelGGL(gemm_y, dim3(16, 7, 2), dim3(256), 0, stream, Wo, h_t, b_out, Y);
    hipLaunchKernelGGL(softmax_out, dim3(98), dim3(256), 0, stream, Y, out);
}

// Round 2
// 453.800 us; speedup vs baseline: 1.1872x; 1.1872x over previous
//
#include <hip/hip_runtime.h>
#include <hip/hip_bf16.h>

#define BB 2
#define CC 512
#define HH 14
#define WW 14
#define PP 196
#define NSEQ 8
#define NSLICE 8                 // worker WGs per row (64 ch each)
#define NWORK (14 * NSLICE)      // 112
#define FW 16                    // words per counter line (64B)
#define NZERO (2 * PP * FW + PP * 16)  // ucnt + hcnt + dsAcc (f32 zeros)

// counters: ucnt[cell*FW] counts slice publishes (8 = E/TL/ds ready)
//           hcnt[cell*FW] counts bulk-window wave publishes (8 = h_bulk ready)

// ---------------------------------------------------------------------------
// prep: gemm_a (224 WGs) + transpose_wh (256 WGs) + counter/dsAcc zero (1 WG)
// ---------------------------------------------------------------------------
__global__ __launch_bounds__(256) void prep(
    const float* __restrict__ Wx, const float* __restrict__ X,
    const float* __restrict__ b_in, const float* __restrict__ Wh,
    float* __restrict__ A, float* __restrict__ WhT,
    unsigned* __restrict__ cnts /* ucnt, hcnt, dsAcc contiguous */) {
    __shared__ float Ws[32][33], Xs[32][33];
    int bid = blockIdx.x;
    int t = threadIdx.x;
    if (bid < 224) {
        int z = bid / 112, rem = bid % 112;
        int c0 = (rem % 16) * 32, p0 = (rem / 16) * 32;
        int tx = t % 32, ty = t / 32;
        int pl = (t % 16) * 2, cl = (t / 16) * 2;
        float acc[2][2] = {{0.f,0.f},{0.f,0.f}};
        for (int k0 = 0; k0 < CC; k0 += 32) {
            #pragma unroll
            for (int r = 0; r < 4; ++r)
                Ws[ty + 8*r][tx] = Wx[(size_t)(c0 + ty + 8*r) * CC + k0 + tx];
            #pragma unroll
            for (int r = 0; r < 4; ++r) {
                int p = p0 + tx, k = k0 + ty + 8*r;
                Xs[ty + 8*r][tx] = (p < PP) ? X[((size_t)z * CC + k) * PP + p] : 0.f;
            }
            __syncthreads();
            #pragma unroll
            for (int k = 0; k < 32; ++k) {
                float w0 = Ws[cl][k], w1 = Ws[cl+1][k];
                float x0 = Xs[k][pl], x1 = Xs[k][pl+1];
                acc[0][0] += w0*x0; acc[0][1] += w0*x1;
                acc[1][0] += w1*x0; acc[1][1] += w1*x1;
            }
            __syncthreads();
        }
        #pragma unroll
        for (int i = 0; i < 2; ++i)
            #pragma unroll
            for (int j = 0; j < 2; ++j) {
                int c = c0 + cl + i, p = p0 + pl + j;
                if (p < PP) A[((size_t)z * PP + p) * CC + c] = acc[i][j] + b_in[c];
            }
    } else if (bid < 480) {
        int tid = bid - 224;
        int c0 = (tid % 16) * 32, k0 = (tid / 16) * 32;
        int tx = t % 32, ty = t / 32;
        #pragma unroll
        for (int r = 0; r < 4; ++r)
            Ws[ty + 8*r][tx] = Wh[(size_t)(c0 + ty + 8*r) * CC + k0 + tx];
        __syncthreads();
        #pragma unroll
        for (int r = 0; r < 4; ++r)
            WhT[(size_t)(k0 + ty + 8*r) * CC + c0 + tx] = Ws[tx][ty + 8*r];
    } else {
        for (int i = t; i < NZERO; i += 256) cnts[i] = 0u;
    }
}

// ---------------------------------------------------------------------------
// sync primitives
// ---------------------------------------------------------------------------
__device__ __forceinline__ unsigned flag_ld(const unsigned* f) {
    return __hip_atomic_load(f, __ATOMIC_RELAXED, __HIP_MEMORY_SCOPE_AGENT);
}
__device__ __forceinline__ float ldf_agent(const float* p) {
    return __hip_atomic_load(p, __ATOMIC_RELAXED, __HIP_MEMORY_SCOPE_AGENT);
}
__device__ __forceinline__ void store_wt(float* p, float v) {
    __hip_atomic_store(p, v, __ATOMIC_RELAXED, __HIP_MEMORY_SCOPE_AGENT);
}

// one window pixel for 8 channels (this wave's seq); E = exp(U) input
__device__ __forceinline__ void pix(const float4 E0, const float4 E1,
                                    const float* ar, const float* er, float* hacc) {
    float ee[8] = {E0.x,E0.y,E0.z,E0.w,E1.x,E1.y,E1.z,E1.w};
    float ds = 0.f, tl[8];
    #pragma unroll
    for (int j = 0; j < 8; ++j) {
        float sv = ar[j] + __logf(ee[j]);
        float pv = er[j] * ee[j];
        ds += fmaxf(pv, 1.0f);
        tl[j] = fmaxf(sv, 0.0f) * pv;
    }
    #pragma unroll
    for (int off = 32; off; off >>= 1) ds += __shfl_xor(ds, off, 64);
    float rd = 1.0f / ds;
    #pragma unroll
    for (int j = 0; j < 8; ++j) hacc[j] += tl[j] * rd;
}

// process n pixels at rowp + y*CC, 4-deep pipelined plain loads
__device__ __forceinline__ void proc_row(const float* __restrict__ rowp, int n,
                                         const float* ar, const float* er, float* hacc) {
    float4 cur[4][2];
    int y = 0, curn = (n < 4) ? n : 4;
    #pragma unroll
    for (int i = 0; i < 4; ++i) if (i < curn) {
        cur[i][0] = *(const float4*)(rowp + (size_t)i * CC);
        cur[i][1] = *(const float4*)(rowp + (size_t)i * CC + 256);
    }
    while (true) {
        int yn = y + curn;
        int rem = n - yn;
        int nextn = (rem < 4) ? rem : 4;
        float4 nxt[4][2];
        #pragma unroll
        for (int i = 0; i < 4; ++i) if (i < nextn) {
            nxt[i][0] = *(const float4*)(rowp + (size_t)(yn + i) * CC);
            nxt[i][1] = *(const float4*)(rowp + (size_t)(yn + i) * CC + 256);
        }
        #pragma unroll
        for (int i = 0; i < 4; ++i) if (i < curn)
            pix(cur[i][0], cur[i][1], ar, er, hacc);
        if (nextn <= 0) break;
        #pragma unroll
        for (int i = 0; i < 4; ++i) if (i < nextn) {
            cur[i][0] = nxt[i][0]; cur[i][1] = nxt[i][1];
        }
        curn = nextn; y = yn;
    }
}

// ---------------------------------------------------------------------------
// One kernel, two roles:
//   blockIdx 0..111   : row workers (row=bid>>3, 64-ch slice).
//     Producer-side tail precompute: at publish, each slice computes for its
//     South/East consumer cells tl = max(a_cons+U,0)*exp(a_cons)*E and
//     per-slice denominator partials (f32 global atomics into dsAcc). The
//     consumer does h = hb + tlN*rcp(dsN) + tlW*rcp(dsW) -- no logs, no
//     full-channel shuffle reduce, no cross-wave barrier dance.
//     Matvec k-split per wave (wave w owns k in [64w,64w+64)), fragments read
//     as wave-uniform ds_read_b128 from stride-8 hT8 (LDS broadcast),
//     partials to per-wave LDS buffer, publish sums 8 -- no 160-shfl tree.
//     NOTE: __launch_bounds__(512, 2): VGPR cap 128 (wreg2[64] must stay in
//     registers -- (512,4) capped at 64 VGPR and spilled it to scratch:
//     +71 MB HBM traffic, 388->415 us regression in round 1).
//   blockIdx 112..307 : per-cell bulk WGs -- unchanged.
// ---------------------------------------------------------------------------
__global__ __launch_bounds__(512, 2) void rnn_dataflow(
    const float* __restrict__ A, const float* __restrict__ WhT,
    float* __restrict__ E, float* __restrict__ h_bulk,
    float* __restrict__ h_t, float* __restrict__ TLN,
    float* __restrict__ TLW, float* __restrict__ dsAcc,
    unsigned* __restrict__ ucnt, unsigned* __restrict__ hcnt) {
    __shared__ __align__(16) float hT8[CC * 8];   // full h [k][s], stride 8
    __shared__ __align__(16) float up[8 * 576];   // matvec partials [wave][c*9+s]
    __shared__ unsigned mbox;                     // bulk WG: ready-rows bitmap
    int bid = blockIdx.x;
    int t = threadIdx.x;
    int lane = t & 63, wv = t >> 6;

    if (bid < NWORK) {
        // ================= row worker =================
        int px = bid >> 3, w = bid & 7;
        int ch = w * 64 + lane;                   // this thread's publish channel
        int m = wv >> 1, b = wv & 1;              // seq decode (s = wv)
        float wreg2[64];                          // WhT[64wv+kk][ch]
        #pragma unroll
        for (int kk = 0; kk < 64; ++kk)
            wreg2[kk] = WhT[(size_t)(wv * 64 + kk) * CC + ch];
        __builtin_amdgcn_s_setprio(1);

        for (int py = 0; py < WW; ++py) {
            int cell = px * WW + py;
            int cellN = cell - WW, cellW = cell - 1;

            // prefetch consumer-cell a values (overlaps the poll)
            float aSr = 0.f, aWr = 0.f;
            if (px < HH - 1) {
                int fi = (m & 2) ? (HH - 2 - px) : (px + 1);
                int fj = (m & 1) ? (WW - 1 - py) : py;
                aSr = A[((size_t)b * PP + fi * WW + fj) * CC + ch];
            }
            if (py < WW - 1) {
                int fi = (m & 2) ? (HH - 1 - px) : px;
                int fj = (m & 1) ? (WW - 2 - py) : (py + 1);
                aWr = A[((size_t)b * PP + fi * WW + fj) * CC + ch];
            }

            // merged poll: ONE lane per counter (lanes 0:N, 1:W, 2:h_bulk)
            if (wv == 0) {
                while (true) {
                    unsigned ok = 1u;
                    if (lane == 0)      { if (px > 0) ok = (flag_ld(ucnt + (size_t)cellN * FW) >= 8u); }
                    else if (lane == 1) { if (py > 0) ok = (flag_ld(ucnt + (size_t)cellW * FW) >= 8u); }
                    else if (lane == 2) ok = (flag_ld(hcnt + (size_t)cell * FW) >= 8u);
                    if (__ballot(ok != 0u) == ~0ull) break;
                    __builtin_amdgcn_s_sleep(1);
                }
            }
            __syncthreads();
            asm volatile("" ::: "memory");

            // stage: h_bulk + producer-precomputed tails (channel = t).
            // Accumulate directly into hb[] to keep peak VGPR pressure low.
            float hb[8];
            #pragma unroll
            for (int s = 0; s < 8; ++s)
                hb[s] = h_bulk[((size_t)cell * NSEQ + s) * CC + t];
            float ds16[16];
            if (px > 0) {
                #pragma unroll
                for (int i = 0; i < 8; ++i)
                    ds16[i] = ldf_agent(&dsAcc[(size_t)cell * 16 + i]);
            }
            if (py > 0) {
                #pragma unroll
                for (int i = 8; i < 16; ++i)
                    ds16[i] = ldf_agent(&dsAcc[(size_t)cell * 16 + i]);
            }
            if (px > 0) {
                #pragma unroll
                for (int s = 0; s < 8; ++s)
                    hb[s] += ldf_agent(&TLN[((size_t)cell * NSEQ + s) * CC + t])
                             * __builtin_amdgcn_rcpf(ds16[s]);
            }
            if (py > 0) {
                #pragma unroll
                for (int s = 0; s < 8; ++s)
                    hb[s] += ldf_agent(&TLW[((size_t)cell * NSEQ + s) * CC + t])
                             * __builtin_amdgcn_rcpf(ds16[8 + s]);
            }
            if (w == 0) {
                #pragma unroll
                for (int s = 0; s < 8; ++s)
                    h_t[((size_t)cell * NSEQ + s) * CC + t] = hb[s];  // for gemm_y
            }
            *(float4*)&hT8[t * 8]     = make_float4(hb[0], hb[1], hb[2], hb[3]);
            *(float4*)&hT8[t * 8 + 4] = make_float4(hb[4], hb[5], hb[6], hb[7]);
            __syncthreads();
            if (cell == PP - 1) break;           // (13,13): no U consumer

            // matvec: wave wv owns k in [64wv, 64wv+64); lane owns channel.
            // hT8 reads are wave-uniform b128 (LDS broadcast, conflict-free).
            float acc[8] = {0.f,0.f,0.f,0.f,0.f,0.f,0.f,0.f};
            const float* hp = hT8 + (wv << 9);
            #pragma unroll
            for (int kk = 0; kk < 64; ++kk) {
                float4 h0 = *(const float4*)(hp + kk * 8);
                float4 h1 = *(const float4*)(hp + kk * 8 + 4);
                float wvv = wreg2[kk];
                acc[0] += wvv * h0.x; acc[1] += wvv * h0.y;
                acc[2] += wvv * h0.z; acc[3] += wvv * h0.w;
                acc[4] += wvv * h1.x; acc[5] += wvv * h1.y;
                acc[6] += wvv * h1.z; acc[7] += wvv * h1.w;
            }
            #pragma unroll
            for (int s = 0; s < 8; ++s)
                up[wv * 576 + lane * 9 + s] = acc[s];   // full overwrite, no zeroing
            __syncthreads();

            // publish: U, E = exp(U), consumer tails + denominator partials
            {
                float U = up[lane * 9 + wv];
                #pragma unroll
                for (int w2 = 1; w2 < 8; ++w2) U += up[w2 * 576 + lane * 9 + wv];
                float Ev = __expf(U);
                store_wt(&E[((size_t)wv * PP + cell) * CC + ch], Ev);
                float pdS = 0.f, pdW = 0.f;
                if (px < HH - 1) {
                    float pv = __expf(aSr) * Ev;
                    store_wt(&TLN[((size_t)(cell + WW) * NSEQ + wv) * CC + ch],
                             fmaxf(aSr + U, 0.f) * pv);
                    pdS = fmaxf(pv, 1.f);
                }
                if (py < WW - 1) {
                    float pv = __expf(aWr) * Ev;
                    store_wt(&TLW[((size_t)(cell + 1) * NSEQ + wv) * CC + ch],
                             fmaxf(aWr + U, 0.f) * pv);
                    pdW = fmaxf(pv, 1.f);
                }
                #pragma unroll
                for (int off = 32; off; off >>= 1) {
                    pdS += __shfl_xor(pdS, off, 64);
                    pdW += __shfl_xor(pdW, off, 64);
                }
                if (lane == 0) {
                    if (px < HH - 1)
                        unsafeAtomicAdd(&dsAcc[(size_t)(cell + WW) * 16 + wv], pdS);
                    if (py < WW - 1)
                        unsafeAtomicAdd(&dsAcc[(size_t)(cell + 1) * 16 + 8 + wv], pdW);
                }
            }
            __syncthreads();     // all waves' stores/atomics drained (vmcnt 0 @ barrier)
            if (t == 0) atomicAdd(ucnt + (size_t)cell * FW, 1u);
        }
    } else {
        // ================= bulk window WG (self + slack>=2), off-path =======
        int cell = bid - NWORK;
        int px = cell / WW, py = cell % WW;
        int s = wv, m = s >> 1, b = s & 1;
        int fi = (m & 2) ? (HH-1-px) : px;
        int fj = (m & 1) ? (WW-1-py) : py;
        int cb = lane * 4;

        if (t == 0) mbox = 0u;
        __syncthreads();          // once, at WG start (long before deps ready)

        const float* acur = A + ((size_t)b * PP + fi * WW + fj) * CC;
        float4 a0 = *(const float4*)(acur + cb);
        float4 a1 = *(const float4*)(acur + cb + 256);
        float ar[8] = {a0.x,a0.y,a0.z,a0.w,a1.x,a1.y,a1.z,a1.w};
        float er[8];
        #pragma unroll
        for (int j = 0; j < 8; ++j) er[j] = __expf(ar[j]);
        float hacc[8] = {0.f,0.f,0.f,0.f,0.f,0.f,0.f,0.f};

        {   // self pixel first (needs no U at all): U=0 -> E=1
            float ds = 0.f, tl[8];
            #pragma unroll
            for (int j = 0; j < 8; ++j) {
                float pv = er[j];
                ds += fmaxf(pv, 1.0f);
                tl[j] = fmaxf(ar[j], 0.0f) * pv;
            }
            #pragma unroll
            for (int off = 32; off; off >>= 1) ds += __shfl_xor(ds, off, 64);
            float rd = 1.0f / ds;
            #pragma unroll
            for (int j = 0; j < 8; ++j) hacc[j] += tl[j] * rd;
        }

        const float* Eb = E + (size_t)s * PP * CC;
        // bulk rows: x<=px-2 -> y<=py ; x=px-1 -> y<=py-1 ; x=px -> y<=py-2
        unsigned pend = 0u;
        for (int x = 0; x <= px; ++x) {
            int yl = (x <= px-2) ? py : ((x == px-1) ? py-1 : py-2);
            if (yl >= 0) pend |= (1u << x);
        }
        if (wv == 0) {
            // sole fabric poller: lane r checks row r's tail counter
            unsigned done = 0u;
            while (pend) {
                bool rdy = true;
                if (lane <= px && (pend & (1u << lane))) {
                    int yl = (lane <= px-2) ? py : ((lane == px-1) ? py-1 : py-2);
                    rdy = flag_ld(ucnt + (size_t)(lane * WW + yl) * FW) >= 8u;
                }
                unsigned long long bal = __ballot(rdy);
                unsigned newly = 0u, rem2 = pend;
                while (rem2) {
                    int x = __ffs(rem2) - 1; rem2 &= rem2 - 1;
                    if ((bal >> x) & 1ull) newly |= 1u << x;
                }
                if (!newly) { __builtin_amdgcn_s_sleep(2); continue; }
                done |= newly;
                __hip_atomic_store(&mbox, done, __ATOMIC_RELAXED,
                                   __HIP_MEMORY_SCOPE_WORKGROUP);
                asm volatile("" ::: "memory");
                unsigned go = newly;
                while (go) {
                    int x = __ffs(go) - 1; go &= go - 1;
                    int yl = (x <= px-2) ? py : ((x == px-1) ? py-1 : py-2);
                    proc_row(Eb + (size_t)(x * WW) * CC + cb, yl + 1, ar, er, hacc);
                }
                pend &= ~newly;
            }
        } else {
            while (pend) {
                unsigned d = __hip_atomic_load(&mbox, __ATOMIC_RELAXED,
                                               __HIP_MEMORY_SCOPE_WORKGROUP);
                unsigned newly = d & pend;
                if (!newly) { __builtin_amdgcn_s_sleep(2); continue; }
                asm volatile("" ::: "memory");
                unsigned go = newly;
                while (go) {
                    int x = __ffs(go) - 1; go &= go - 1;
                    int yl = (x <= px-2) ? py : ((x == px-1) ? py-1 : py-2);
                    proc_row(Eb + (size_t)(x * WW) * CC + cb, yl + 1, ar, er, hacc);
                }
                pend &= ~newly;
            }
        }

        // per-wave publish h_bulk: contiguous WT stores + drain + counter
        float* hp = h_bulk + ((size_t)cell * NSEQ + s) * CC;
        #pragma unroll
        for (int j = 0; j < 4; ++j) {
            store_wt(hp + cb + j,       hacc[j]);
            store_wt(hp + cb + 256 + j, hacc[4 + j]);
        }
        __builtin_amdgcn_s_waitcnt(0);
        asm volatile("" ::: "memory");
        if (lane == 0) atomicAdd(hcnt + (size_t)cell * FW, 1u);
    }
}

// ---------------------------------------------------------------------------
// gemm_y: Y[b][p][c] = sum_k Wo[c][k] * (sum_m h_t[p][2m+b][k]) + 4*b_out[c]
// ---------------------------------------------------------------------------
__global__ __launch_bounds__(256) void gemm_y(
    const float* __restrict__ Wo, const float* __restrict__ h_t,
    const float* __restrict__ b_out, float* __restrict__ Y) {
    __shared__ float Ws[32][33], Hs[32][33];
    int b  = blockIdx.z;
    int c0 = blockIdx.x * 32, p0 = blockIdx.y * 32;
    int t  = threadIdx.x;
    int tx = t % 32, ty = t / 32;
    int pl = (t % 16) * 2, cl = (t / 16) * 2;
    float acc[2][2] = {{0.f,0.f},{0.f,0.f}};
    for (int k0 = 0; k0 < CC; k0 += 32) {
        #pragma unroll
        for (int r = 0; r < 4; ++r)
            Ws[ty + 8*r][tx] = Wo[(size_t)(c0 + ty + 8*r) * CC + k0 + tx];
        #pragma unroll
        for (int r = 0; r < 4; ++r) {
            int p = p0 + ty + 8*r;
            float v = 0.f;
            if (p < PP) {
                size_t base = (size_t)p * NSEQ * CC + k0 + tx;
                v = h_t[base + (size_t)(0 + b) * CC]
                  + h_t[base + (size_t)(2 + b) * CC]
                  + h_t[base + (size_t)(4 + b) * CC]
                  + h_t[base + (size_t)(6 + b) * CC];
            }
            Hs[tx][ty + 8*r] = v;
        }
        __syncthreads();
        #pragma unroll
        for (int k = 0; k < 32; ++k) {
            float w0 = Ws[cl][k], w1 = Ws[cl+1][k];
            float h0 = Hs[k][pl], h1 = Hs[k][pl+1];
            acc[0][0] += w0*h0; acc[0][1] += w0*h1;
            acc[1][0] += w1*h0; acc[1][1] += w1*h1;
        }
        __syncthreads();
    }
    #pragma unroll
    for (int i = 0; i < 2; ++i)
        #pragma unroll
        for (int j = 0; j < 2; ++j) {
            int cc = c0 + cl + i, p = p0 + pl + j;
            if (p < PP) Y[((size_t)b * PP + p) * CC + cc] = acc[i][j] + 4.0f * b_out[cc];
        }
}

// ---------------------------------------------------------------------------
// softmax over channels -> out[b][c][p]
// ---------------------------------------------------------------------------
__global__ __launch_bounds__(256) void softmax_out(
    const float* __restrict__ Y, float* __restrict__ out) {
    int wave = threadIdx.x >> 6, lane = threadIdx.x & 63;
    int idx = blockIdx.x * 4 + wave;
    if (idx >= BB * PP) return;
    int b = idx / PP, p = idx % PP;
    const float* y = Y + ((size_t)b * PP + p) * CC;
    float v[8];
    float mx = -3.4e38f;
    #pragma unroll
    for (int j = 0; j < 8; ++j) { v[j] = y[lane + 64*j]; mx = fmaxf(mx, v[j]); }
    #pragma unroll
    for (int off = 32; off; off >>= 1) mx = fmaxf(mx, __shfl_xor(mx, off, 64));
    float sum = 0.f;
    #pragma unroll
    for (int j = 0; j < 8; ++j) { v[j] = expf(v[j] - mx); sum += v[j]; }
    #pragma unroll
    for (int off = 32; off; off >>= 1) sum += __shfl_xor(sum, off, 64);
    float r = 1.0f / sum;
    #pragma unroll
    for (int j = 0; j < 8; ++j)
        out[((size_t)b * CC + lane + 64*j) * PP + p] = v[j] * r;
}

// ---------------------------------------------------------------------------
extern "C" void kernel_launch(void* const* d_in, const int* in_sizes, int n_in,
                              void* d_out, int out_size, void* d_ws, size_t ws_size,
                              hipStream_t stream) {
    const float* X     = (const float*)d_in[0];
    const float* Wx    = (const float*)d_in[1];
    const float* Wh    = (const float*)d_in[2];
    const float* b_in  = (const float*)d_in[3];
    const float* Wo    = (const float*)d_in[4];
    const float* b_out = (const float*)d_in[5];
    float* out = (float*)d_out;

    float* ws     = (float*)d_ws;
    float* WhT    = ws;                     // 262144
    float* A      = WhT    + 262144;        // 200704
    float* E      = A      + 200704;        // 802816  [s][cell][c] = exp(U)
    float* h_bulk = E      + 802816;        // 802816  [cell][s][c]
    float* h_t    = h_bulk + 802816;        // 802816  [cell][s][c] full h
    float* TLN    = h_t    + 802816;        // 802816  [cell][s][c] tail from North
    float* TLW    = TLN    + 802816;        // 802816  [cell][s][c] tail from West
    float* Y      = TLW    + 802816;        // 200704
    unsigned* ucnt = (unsigned*)(Y + 200704);       // PP*FW
    unsigned* hcnt = ucnt + PP * FW;                // PP*FW
    float* dsAcc   = (float*)(hcnt + PP * FW);      // PP*16: [cell][N:0-7|W:8-15]

    hipLaunchKernelGGL(prep, dim3(481), dim3(256), 0, stream,
                       Wx, X, b_in, Wh, A, WhT, ucnt);
    hipLaunchKernelGGL(rnn_dataflow, dim3(NWORK + PP), dim3(512), 0, stream,
                       A, WhT, E, h_bulk, h_t, TLN, TLW, dsAcc, ucnt, hcnt);
    hipLaunchKernelGGL(gemm_y, dim3(16, 7, 2), dim3(256), 0, stream, Wo, h_t, b_out, Y);
    hipLaunchKernelGGL(softmax_out, dim3(98), dim3(256), 0, stream, Y, out);
}

// Round 3
// 362.026 us; speedup vs baseline: 1.4882x; 1.2535x over previous
//
#include <hip/hip_runtime.h>
#include <hip/hip_bf16.h>

#define BB 2
#define CC 512
#define HH 14
#define WW 14
#define PP 196
#define NSEQ 8
#define NSLICE 8                 // worker WGs per row (64 ch each)
#define NWORK (14 * NSLICE)      // 112
#define FW 16                    // words per counter line (64B)
#define NZERO (2 * PP * FW + PP * 16)  // ucnt + hcnt + dsAcc (f32 zeros)

// counters: ucnt[cell*FW] counts slice publishes (8 = E/TL/ds ready)
//           hcnt[cell*FW] counts bulk-window wave publishes (8 = h_bulk ready)

// ---------------------------------------------------------------------------
// prep: gemm_a (224 WGs) + transpose_wh (256 WGs) + counter/dsAcc zero (1 WG)
// ---------------------------------------------------------------------------
__global__ __launch_bounds__(256) void prep(
    const float* __restrict__ Wx, const float* __restrict__ X,
    const float* __restrict__ b_in, const float* __restrict__ Wh,
    float* __restrict__ A, float* __restrict__ WhT,
    unsigned* __restrict__ cnts /* ucnt, hcnt, dsAcc contiguous */) {
    __shared__ float Ws[32][33], Xs[32][33];
    int bid = blockIdx.x;
    int t = threadIdx.x;
    if (bid < 224) {
        int z = bid / 112, rem = bid % 112;
        int c0 = (rem % 16) * 32, p0 = (rem / 16) * 32;
        int tx = t % 32, ty = t / 32;
        int pl = (t % 16) * 2, cl = (t / 16) * 2;
        float acc[2][2] = {{0.f,0.f},{0.f,0.f}};
        for (int k0 = 0; k0 < CC; k0 += 32) {
            #pragma unroll
            for (int r = 0; r < 4; ++r)
                Ws[ty + 8*r][tx] = Wx[(size_t)(c0 + ty + 8*r) * CC + k0 + tx];
            #pragma unroll
            for (int r = 0; r < 4; ++r) {
                int p = p0 + tx, k = k0 + ty + 8*r;
                Xs[ty + 8*r][tx] = (p < PP) ? X[((size_t)z * CC + k) * PP + p] : 0.f;
            }
            __syncthreads();
            #pragma unroll
            for (int k = 0; k < 32; ++k) {
                float w0 = Ws[cl][k], w1 = Ws[cl+1][k];
                float x0 = Xs[k][pl], x1 = Xs[k][pl+1];
                acc[0][0] += w0*x0; acc[0][1] += w0*x1;
                acc[1][0] += w1*x0; acc[1][1] += w1*x1;
            }
            __syncthreads();
        }
        #pragma unroll
        for (int i = 0; i < 2; ++i)
            #pragma unroll
            for (int j = 0; j < 2; ++j) {
                int c = c0 + cl + i, p = p0 + pl + j;
                if (p < PP) A[((size_t)z * PP + p) * CC + c] = acc[i][j] + b_in[c];
            }
    } else if (bid < 480) {
        int tid = bid - 224;
        int c0 = (tid % 16) * 32, k0 = (tid / 16) * 32;
        int tx = t % 32, ty = t / 32;
        #pragma unroll
        for (int r = 0; r < 4; ++r)
            Ws[ty + 8*r][tx] = Wh[(size_t)(c0 + ty + 8*r) * CC + k0 + tx];
        __syncthreads();
        #pragma unroll
        for (int r = 0; r < 4; ++r)
            WhT[(size_t)(k0 + ty + 8*r) * CC + c0 + tx] = Ws[tx][ty + 8*r];
    } else {
        for (int i = t; i < NZERO; i += 256) cnts[i] = 0u;
    }
}

// ---------------------------------------------------------------------------
// sync primitives
// ---------------------------------------------------------------------------
__device__ __forceinline__ unsigned flag_ld(const unsigned* f) {
    return __hip_atomic_load(f, __ATOMIC_RELAXED, __HIP_MEMORY_SCOPE_AGENT);
}
__device__ __forceinline__ float ldf_agent(const float* p) {
    return __hip_atomic_load(p, __ATOMIC_RELAXED, __HIP_MEMORY_SCOPE_AGENT);
}
__device__ __forceinline__ void store_wt(float* p, float v) {
    __hip_atomic_store(p, v, __ATOMIC_RELAXED, __HIP_MEMORY_SCOPE_AGENT);
}

// one window pixel for 8 channels (this wave's seq); E = exp(U) input
__device__ __forceinline__ void pix(const float4 E0, const float4 E1,
                                    const float* ar, const float* er, float* hacc) {
    float ee[8] = {E0.x,E0.y,E0.z,E0.w,E1.x,E1.y,E1.z,E1.w};
    float ds = 0.f, tl[8];
    #pragma unroll
    for (int j = 0; j < 8; ++j) {
        float sv = ar[j] + __logf(ee[j]);
        float pv = er[j] * ee[j];
        ds += fmaxf(pv, 1.0f);
        tl[j] = fmaxf(sv, 0.0f) * pv;
    }
    #pragma unroll
    for (int off = 32; off; off >>= 1) ds += __shfl_xor(ds, off, 64);
    float rd = 1.0f / ds;
    #pragma unroll
    for (int j = 0; j < 8; ++j) hacc[j] += tl[j] * rd;
}

// process n pixels at rowp + y*CC, 4-deep pipelined plain loads
__device__ __forceinline__ void proc_row(const float* __restrict__ rowp, int n,
                                         const float* ar, const float* er, float* hacc) {
    float4 cur[4][2];
    int y = 0, curn = (n < 4) ? n : 4;
    #pragma unroll
    for (int i = 0; i < 4; ++i) if (i < curn) {
        cur[i][0] = *(const float4*)(rowp + (size_t)i * CC);
        cur[i][1] = *(const float4*)(rowp + (size_t)i * CC + 256);
    }
    while (true) {
        int yn = y + curn;
        int rem = n - yn;
        int nextn = (rem < 4) ? rem : 4;
        float4 nxt[4][2];
        #pragma unroll
        for (int i = 0; i < 4; ++i) if (i < nextn) {
            nxt[i][0] = *(const float4*)(rowp + (size_t)(yn + i) * CC);
            nxt[i][1] = *(const float4*)(rowp + (size_t)(yn + i) * CC + 256);
        }
        #pragma unroll
        for (int i = 0; i < 4; ++i) if (i < curn)
            pix(cur[i][0], cur[i][1], ar, er, hacc);
        if (nextn <= 0) break;
        #pragma unroll
        for (int i = 0; i < 4; ++i) if (i < nextn) {
            cur[i][0] = nxt[i][0]; cur[i][1] = nxt[i][1];
        }
        curn = nextn; y = yn;
    }
}

// ---------------------------------------------------------------------------
// One kernel, two roles:
//   blockIdx 0..111   : row workers (row=bid>>3, 64-ch slice).
//     Producer-side tails (round 2). Round 3: split poll -- hcnt first (bulk
//     has >=2 cells slack, nearly always ready), h_bulk loads issued so their
//     latency hides under the N/W ucnt wait; h_t stores split per-slice
//     (slice 0 was writing 16KB/cell while siblings wrote 0 -- row cadence
//     followed the laggard).
//   blockIdx 112..307 : per-cell bulk WGs. Round 3: every window row split
//     into an early chunk [0..L-3] (gated 3 cells early, off the critical
//     window) and a late chunk [L-2..L] (<=3 pixels, gated on the row's last
//     counter). The critical h_bulk publish window now contains a 3-pixel
//     load+compute instead of an entire up-to-12-pixel row.
// ---------------------------------------------------------------------------
__global__ __launch_bounds__(512, 2) void rnn_dataflow(
    const float* __restrict__ A, const float* __restrict__ WhT,
    float* __restrict__ E, float* __restrict__ h_bulk,
    float* __restrict__ h_t, float* __restrict__ TLN,
    float* __restrict__ TLW, float* __restrict__ dsAcc,
    unsigned* __restrict__ ucnt, unsigned* __restrict__ hcnt) {
    __shared__ __align__(16) float hT8[CC * 8];   // full h [k][s], stride 8
    __shared__ __align__(16) float up[8 * 576];   // matvec partials [wave][c*9+s]
    __shared__ unsigned mbox;                     // bulk WG: ready-chunks bitmap
    int bid = blockIdx.x;
    int t = threadIdx.x;
    int lane = t & 63, wv = t >> 6;

    if (bid < NWORK) {
        // ================= row worker =================
        int px = bid >> 3, w = bid & 7;
        int ch = w * 64 + lane;                   // this thread's publish channel
        int m = wv >> 1, b = wv & 1;              // seq decode (s = wv)
        float wreg2[64];                          // WhT[64wv+kk][ch]
        #pragma unroll
        for (int kk = 0; kk < 64; ++kk)
            wreg2[kk] = WhT[(size_t)(wv * 64 + kk) * CC + ch];
        __builtin_amdgcn_s_setprio(1);

        for (int py = 0; py < WW; ++py) {
            int cell = px * WW + py;
            int cellN = cell - WW, cellW = cell - 1;

            // prefetch consumer-cell a values (overlaps the polls)
            float aSr = 0.f, aWr = 0.f;
            if (px < HH - 1) {
                int fi = (m & 2) ? (HH - 2 - px) : (px + 1);
                int fj = (m & 1) ? (WW - 1 - py) : py;
                aSr = A[((size_t)b * PP + fi * WW + fj) * CC + ch];
            }
            if (py < WW - 1) {
                int fi = (m & 2) ? (HH - 1 - px) : px;
                int fj = (m & 1) ? (WW - 2 - py) : (py + 1);
                aWr = A[((size_t)b * PP + fi * WW + fj) * CC + ch];
            }

            // phase 1: bulk h ready? (chunked bulk publishes with slack)
            if (wv == 0 && lane == 0)
                while (flag_ld(hcnt + (size_t)cell * FW) < 8u)
                    __builtin_amdgcn_s_sleep(1);
            __syncthreads();
            asm volatile("" ::: "memory");
            float hb[8];
            #pragma unroll
            for (int s = 0; s < 8; ++s)
                hb[s] = h_bulk[((size_t)cell * NSEQ + s) * CC + t];

            // phase 2: N/W publishes ready? (hb loads in flight during wait)
            if (wv == 0) {
                while (true) {
                    unsigned ok = 1u;
                    if (lane == 0)      { if (px > 0) ok = (flag_ld(ucnt + (size_t)cellN * FW) >= 8u); }
                    else if (lane == 1) { if (py > 0) ok = (flag_ld(ucnt + (size_t)cellW * FW) >= 8u); }
                    if (__ballot(ok != 0u) == ~0ull) break;
                    __builtin_amdgcn_s_sleep(1);
                }
            }
            __syncthreads();
            asm volatile("" ::: "memory");

            // stage producer-precomputed tails (channel = t) into hb
            float ds16[16];
            if (px > 0) {
                #pragma unroll
                for (int i = 0; i < 8; ++i)
                    ds16[i] = ldf_agent(&dsAcc[(size_t)cell * 16 + i]);
            }
            if (py > 0) {
                #pragma unroll
                for (int i = 8; i < 16; ++i)
                    ds16[i] = ldf_agent(&dsAcc[(size_t)cell * 16 + i]);
            }
            if (px > 0) {
                #pragma unroll
                for (int s = 0; s < 8; ++s)
                    hb[s] += ldf_agent(&TLN[((size_t)cell * NSEQ + s) * CC + t])
                             * __builtin_amdgcn_rcpf(ds16[s]);
            }
            if (py > 0) {
                #pragma unroll
                for (int s = 0; s < 8; ++s)
                    hb[s] += ldf_agent(&TLW[((size_t)cell * NSEQ + s) * CC + t])
                             * __builtin_amdgcn_rcpf(ds16[8 + s]);
            }
            if ((t >> 6) == w) {   // h_t: this slice's own 64-ch stripe only
                #pragma unroll
                for (int s = 0; s < 8; ++s)
                    h_t[((size_t)cell * NSEQ + s) * CC + t] = hb[s];
            }
            *(float4*)&hT8[t * 8]     = make_float4(hb[0], hb[1], hb[2], hb[3]);
            *(float4*)&hT8[t * 8 + 4] = make_float4(hb[4], hb[5], hb[6], hb[7]);
            __syncthreads();
            if (cell == PP - 1) break;           // (13,13): no U consumer

            // matvec: wave wv owns k in [64wv, 64wv+64); lane owns channel.
            // hT8 reads are wave-uniform b128 (LDS broadcast, conflict-free).
            float acc[8] = {0.f,0.f,0.f,0.f,0.f,0.f,0.f,0.f};
            const float* hp = hT8 + (wv << 9);
            #pragma unroll
            for (int kk = 0; kk < 64; ++kk) {
                float4 h0 = *(const float4*)(hp + kk * 8);
                float4 h1 = *(const float4*)(hp + kk * 8 + 4);
                float wvv = wreg2[kk];
                acc[0] += wvv * h0.x; acc[1] += wvv * h0.y;
                acc[2] += wvv * h0.z; acc[3] += wvv * h0.w;
                acc[4] += wvv * h1.x; acc[5] += wvv * h1.y;
                acc[6] += wvv * h1.z; acc[7] += wvv * h1.w;
            }
            #pragma unroll
            for (int s = 0; s < 8; ++s)
                up[wv * 576 + lane * 9 + s] = acc[s];   // full overwrite, no zeroing
            __syncthreads();

            // publish: U, E = exp(U), consumer tails + denominator partials
            {
                float U = up[lane * 9 + wv];
                #pragma unroll
                for (int w2 = 1; w2 < 8; ++w2) U += up[w2 * 576 + lane * 9 + wv];
                float Ev = __expf(U);
                store_wt(&E[((size_t)wv * PP + cell) * CC + ch], Ev);
                float pdS = 0.f, pdW = 0.f;
                if (px < HH - 1) {
                    float pv = __expf(aSr) * Ev;
                    store_wt(&TLN[((size_t)(cell + WW) * NSEQ + wv) * CC + ch],
                             fmaxf(aSr + U, 0.f) * pv);
                    pdS = fmaxf(pv, 1.f);
                }
                if (py < WW - 1) {
                    float pv = __expf(aWr) * Ev;
                    store_wt(&TLW[((size_t)(cell + 1) * NSEQ + wv) * CC + ch],
                             fmaxf(aWr + U, 0.f) * pv);
                    pdW = fmaxf(pv, 1.f);
                }
                #pragma unroll
                for (int off = 32; off; off >>= 1) {
                    pdS += __shfl_xor(pdS, off, 64);
                    pdW += __shfl_xor(pdW, off, 64);
                }
                if (lane == 0) {
                    if (px < HH - 1)
                        unsafeAtomicAdd(&dsAcc[(size_t)(cell + WW) * 16 + wv], pdS);
                    if (py < WW - 1)
                        unsafeAtomicAdd(&dsAcc[(size_t)(cell + 1) * 16 + 8 + wv], pdW);
                }
            }
            __syncthreads();     // all waves' stores/atomics drained (vmcnt 0 @ barrier)
            if (t == 0) atomicAdd(ucnt + (size_t)cell * FW, 1u);
        }
    } else {
        // ================= bulk window WG (chunked rows), off-path ==========
        int cell = bid - NWORK;
        int px = cell / WW, py = cell % WW;
        int s = wv, m = s >> 1, b = s & 1;
        int fi = (m & 2) ? (HH-1-px) : px;
        int fj = (m & 1) ? (WW-1-py) : py;
        int cb = lane * 4;

        if (t == 0) mbox = 0u;
        __syncthreads();          // once, at WG start (long before deps ready)

        const float* acur = A + ((size_t)b * PP + fi * WW + fj) * CC;
        float4 a0 = *(const float4*)(acur + cb);
        float4 a1 = *(const float4*)(acur + cb + 256);
        float ar[8] = {a0.x,a0.y,a0.z,a0.w,a1.x,a1.y,a1.z,a1.w};
        float er[8];
        #pragma unroll
        for (int j = 0; j < 8; ++j) er[j] = __expf(ar[j]);
        float hacc[8] = {0.f,0.f,0.f,0.f,0.f,0.f,0.f,0.f};

        {   // self pixel first (needs no U at all): U=0 -> E=1
            float ds = 0.f, tl[8];
            #pragma unroll
            for (int j = 0; j < 8; ++j) {
                float pv = er[j];
                ds += fmaxf(pv, 1.0f);
                tl[j] = fmaxf(ar[j], 0.0f) * pv;
            }
            #pragma unroll
            for (int off = 32; off; off >>= 1) ds += __shfl_xor(ds, off, 64);
            float rd = 1.0f / ds;
            #pragma unroll
            for (int j = 0; j < 8; ++j) hacc[j] += tl[j] * rd;
        }

        const float* Eb = E + (size_t)s * PP * CC;
        // chunk slots: slot = lane, row x = lane>>1, phase = lane&1.
        // row limit L: x<=px-2 -> py ; x=px-1 -> py-1 ; x=px -> py-2
        //   L<=2 : single chunk [0..L]    gate (x,L)     at slot (2x+0)
        //   L>2  : early [0..L-3]         gate (x,L-3)   at slot (2x+0)
        //          late  [L-2..L] (3 px)  gate (x,L)     at slot (2x+1)
        int sx = lane >> 1, sph = lane & 1;
        int gate = -1;
        if (sx <= px) {
            int L = (sx <= px-2) ? py : ((sx == px-1) ? py-1 : py-2);
            if (L >= 0) {
                if (L <= 2) { if (sph == 0) gate = sx * WW + L; }
                else gate = sx * WW + (sph ? L : (L - 3));
            }
        }
        unsigned pend = (unsigned)__ballot(gate >= 0);

        if (wv == 0) {
            // sole fabric poller: lane l checks its chunk's gate counter
            unsigned done = 0u;
            while (pend) {
                bool rdy = true;
                if (gate >= 0 && ((pend >> lane) & 1u))
                    rdy = flag_ld(ucnt + (size_t)gate * FW) >= 8u;
                unsigned newly = pend & (unsigned)__ballot(rdy);
                if (!newly) { __builtin_amdgcn_s_sleep(2); continue; }
                done |= newly;
                __hip_atomic_store(&mbox, done, __ATOMIC_RELAXED,
                                   __HIP_MEMORY_SCOPE_WORKGROUP);
                asm volatile("" ::: "memory");
                unsigned go = newly;
                while (go) {
                    int sl = __ffs(go) - 1; go &= go - 1;
                    int xx = sl >> 1;
                    int L = (xx <= px-2) ? py : ((xx == px-1) ? py-1 : py-2);
                    int yy0 = 0, yy1 = L;
                    if (L > 2) { if (sl & 1) yy0 = L - 2; else yy1 = L - 3; }
                    proc_row(Eb + (size_t)(xx * WW + yy0) * CC + cb,
                             yy1 - yy0 + 1, ar, er, hacc);
                }
                pend &= ~newly;
            }
        } else {
            while (pend) {
                unsigned d = __hip_atomic_load(&mbox, __ATOMIC_RELAXED,
                                               __HIP_MEMORY_SCOPE_WORKGROUP);
                unsigned newly = d & pend;
                if (!newly) { __builtin_amdgcn_s_sleep(2); continue; }
                asm volatile("" ::: "memory");
                unsigned go = newly;
                while (go) {
                    int sl = __ffs(go) - 1; go &= go - 1;
                    int xx = sl >> 1;
                    int L = (xx <= px-2) ? py : ((xx == px-1) ? py-1 : py-2);
                    int yy0 = 0, yy1 = L;
                    if (L > 2) { if (sl & 1) yy0 = L - 2; else yy1 = L - 3; }
                    proc_row(Eb + (size_t)(xx * WW + yy0) * CC + cb,
                             yy1 - yy0 + 1, ar, er, hacc);
                }
                pend &= ~newly;
            }
        }

        // per-wave publish h_bulk: contiguous WT stores + drain + counter
        float* hp = h_bulk + ((size_t)cell * NSEQ + s) * CC;
        #pragma unroll
        for (int j = 0; j < 4; ++j) {
            store_wt(hp + cb + j,       hacc[j]);
            store_wt(hp + cb + 256 + j, hacc[4 + j]);
        }
        __builtin_amdgcn_s_waitcnt(0);
        asm volatile("" ::: "memory");
        if (lane == 0) atomicAdd(hcnt + (size_t)cell * FW, 1u);
    }
}

// ---------------------------------------------------------------------------
// gemm_y: Y[b][p][c] = sum_k Wo[c][k] * (sum_m h_t[p][2m+b][k]) + 4*b_out[c]
// ---------------------------------------------------------------------------
__global__ __launch_bounds__(256) void gemm_y(
    const float* __restrict__ Wo, const float* __restrict__ h_t,
    const float* __restrict__ b_out, float* __restrict__ Y) {
    __shared__ float Ws[32][33], Hs[32][33];
    int b  = blockIdx.z;
    int c0 = blockIdx.x * 32, p0 = blockIdx.y * 32;
    int t  = threadIdx.x;
    int tx = t % 32, ty = t / 32;
    int pl = (t % 16) * 2, cl = (t / 16) * 2;
    float acc[2][2] = {{0.f,0.f},{0.f,0.f}};
    for (int k0 = 0; k0 < CC; k0 += 32) {
        #pragma unroll
        for (int r = 0; r < 4; ++r)
            Ws[ty + 8*r][tx] = Wo[(size_t)(c0 + ty + 8*r) * CC + k0 + tx];
        #pragma unroll
        for (int r = 0; r < 4; ++r) {
            int p = p0 + ty + 8*r;
            float v = 0.f;
            if (p < PP) {
                size_t base = (size_t)p * NSEQ * CC + k0 + tx;
                v = h_t[base + (size_t)(0 + b) * CC]
                  + h_t[base + (size_t)(2 + b) * CC]
                  + h_t[base + (size_t)(4 + b) * CC]
                  + h_t[base + (size_t)(6 + b) * CC];
            }
            Hs[tx][ty + 8*r] = v;
        }
        __syncthreads();
        #pragma unroll
        for (int k = 0; k < 32; ++k) {
            float w0 = Ws[cl][k], w1 = Ws[cl+1][k];
            float h0 = Hs[k][pl], h1 = Hs[k][pl+1];
            acc[0][0] += w0*h0; acc[0][1] += w0*h1;
            acc[1][0] += w1*h0; acc[1][1] += w1*h1;
        }
        __syncthreads();
    }
    #pragma unroll
    for (int i = 0; i < 2; ++i)
        #pragma unroll
        for (int j = 0; j < 2; ++j) {
            int cc = c0 + cl + i, p = p0 + pl + j;
            if (p < PP) Y[((size_t)b * PP + p) * CC + cc] = acc[i][j] + 4.0f * b_out[cc];
        }
}

// ---------------------------------------------------------------------------
// softmax over channels -> out[b][c][p]
// ---------------------------------------------------------------------------
__global__ __launch_bounds__(256) void softmax_out(
    const float* __restrict__ Y, float* __restrict__ out) {
    int wave = threadIdx.x >> 6, lane = threadIdx.x & 63;
    int idx = blockIdx.x * 4 + wave;
    if (idx >= BB * PP) return;
    int b = idx / PP, p = idx % PP;
    const float* y = Y + ((size_t)b * PP + p) * CC;
    float v[8];
    float mx = -3.4e38f;
    #pragma unroll
    for (int j = 0; j < 8; ++j) { v[j] = y[lane + 64*j]; mx = fmaxf(mx, v[j]); }
    #pragma unroll
    for (int off = 32; off; off >>= 1) mx = fmaxf(mx, __shfl_xor(mx, off, 64));
    float sum = 0.f;
    #pragma unroll
    for (int j = 0; j < 8; ++j) { v[j] = expf(v[j] - mx); sum += v[j]; }
    #pragma unroll
    for (int off = 32; off; off >>= 1) sum += __shfl_xor(sum, off, 64);
    float r = 1.0f / sum;
    #pragma unroll
    for (int j = 0; j < 8; ++j)
        out[((size_t)b * CC + lane + 64*j) * PP + p] = v[j] * r;
}

// ---------------------------------------------------------------------------
extern "C" void kernel_launch(void* const* d_in, const int* in_sizes, int n_in,
                              void* d_out, int out_size, void* d_ws, size_t ws_size,
                              hipStream_t stream) {
    const float* X     = (const float*)d_in[0];
    const float* Wx    = (const float*)d_in[1];
    const float* Wh    = (const float*)d_in[2];
    const float* b_in  = (const float*)d_in[3];
    const float* Wo    = (const float*)d_in[4];
    const float* b_out = (const float*)d_in[5];
    float* out = (float*)d_out;

    float* ws     = (float*)d_ws;
    float* WhT    = ws;                     // 262144
    float* A      = WhT    + 262144;        // 200704
    float* E      = A      + 200704;        // 802816  [s][cell][c] = exp(U)
    float* h_bulk = E      + 802816;        // 802816  [cell][s][c]
    float* h_t    = h_bulk + 802816;        // 802816  [cell][s][c] full h
    float* TLN    = h_t    + 802816;        // 802816  [cell][s][c] tail from North
    float* TLW    = TLN    + 802816;        // 802816  [cell][s][c] tail from West
    float* Y      = TLW    + 802816;        // 200704
    unsigned* ucnt = (unsigned*)(Y + 200704);       // PP*FW
    unsigned* hcnt = ucnt + PP * FW;                // PP*FW
    float* dsAcc   = (float*)(hcnt + PP * FW);      // PP*16: [cell][N:0-7|W:8-15]

    hipLaunchKernelGGL(prep, dim3(481), dim3(256), 0, stream,
                       Wx, X, b_in, Wh, A, WhT, ucnt);
    hipLaunchKernelGGL(rnn_dataflow, dim3(NWORK + PP), dim3(512), 0, stream,
                       A, WhT, E, h_bulk, h_t, TLN, TLW, dsAcc, ucnt, hcnt);
    hipLaunchKernelGGL(gemm_y, dim3(16, 7, 2), dim3(256), 0, stream, Wo, h_t, b_out, Y);
    hipLaunchKernelGGL(softmax_out, dim3(98), dim3(256), 0, stream, Y, out);
}

// Round 4
// 361.350 us; speedup vs baseline: 1.4910x; 1.0019x over previous
//
#include <hip/hip_runtime.h>
#include <hip/hip_bf16.h>

#define BB 2
#define CC 512
#define HH 14
#define WW 14
#define PP 196
#define NSEQ 8
#define NSLICE 8                 // worker WGs per row (64 ch each)
#define NWORK (14 * NSLICE)      // 112
#define FW 16                    // dwords per flag/ds line (64B)
#define NZERO (3 * PP * FW)      // uflag + hflag + dsAcc (all zeroed)
#define ALL8 0x0101010101010101ull

// flags: uflag[cell*64 + w] = 1 byte per slice publish (8 bytes == E/TL/ds ready)
//        hflag[cell*64 + s] = 1 byte per bulk-wave publish (8 bytes == h_bulk ready)
// No atomics on the ready path: producers store bytes (no RMW chain), consumers
// poll ONE 8-byte load per dependency.

// ---------------------------------------------------------------------------
// prep: gemm_a (224 WGs) + transpose_wh (256 WGs) + flag/dsAcc zero (1 WG)
// ---------------------------------------------------------------------------
__global__ __launch_bounds__(256) void prep(
    const float* __restrict__ Wx, const float* __restrict__ X,
    const float* __restrict__ b_in, const float* __restrict__ Wh,
    float* __restrict__ A, float* __restrict__ WhT,
    unsigned* __restrict__ cnts /* uflag, hflag, dsAcc contiguous */) {
    __shared__ float Ws[32][33], Xs[32][33];
    int bid = blockIdx.x;
    int t = threadIdx.x;
    if (bid < 224) {
        int z = bid / 112, rem = bid % 112;
        int c0 = (rem % 16) * 32, p0 = (rem / 16) * 32;
        int tx = t % 32, ty = t / 32;
        int pl = (t % 16) * 2, cl = (t / 16) * 2;
        float acc[2][2] = {{0.f,0.f},{0.f,0.f}};
        for (int k0 = 0; k0 < CC; k0 += 32) {
            #pragma unroll
            for (int r = 0; r < 4; ++r)
                Ws[ty + 8*r][tx] = Wx[(size_t)(c0 + ty + 8*r) * CC + k0 + tx];
            #pragma unroll
            for (int r = 0; r < 4; ++r) {
                int p = p0 + tx, k = k0 + ty + 8*r;
                Xs[ty + 8*r][tx] = (p < PP) ? X[((size_t)z * CC + k) * PP + p] : 0.f;
            }
            __syncthreads();
            #pragma unroll
            for (int k = 0; k < 32; ++k) {
                float w0 = Ws[cl][k], w1 = Ws[cl+1][k];
                float x0 = Xs[k][pl], x1 = Xs[k][pl+1];
                acc[0][0] += w0*x0; acc[0][1] += w0*x1;
                acc[1][0] += w1*x0; acc[1][1] += w1*x1;
            }
            __syncthreads();
        }
        #pragma unroll
        for (int i = 0; i < 2; ++i)
            #pragma unroll
            for (int j = 0; j < 2; ++j) {
                int c = c0 + cl + i, p = p0 + pl + j;
                if (p < PP) A[((size_t)z * PP + p) * CC + c] = acc[i][j] + b_in[c];
            }
    } else if (bid < 480) {
        int tid = bid - 224;
        int c0 = (tid % 16) * 32, k0 = (tid / 16) * 32;
        int tx = t % 32, ty = t / 32;
        #pragma unroll
        for (int r = 0; r < 4; ++r)
            Ws[ty + 8*r][tx] = Wh[(size_t)(c0 + ty + 8*r) * CC + k0 + tx];
        __syncthreads();
        #pragma unroll
        for (int r = 0; r < 4; ++r)
            WhT[(size_t)(k0 + ty + 8*r) * CC + c0 + tx] = Ws[tx][ty + 8*r];
    } else {
        for (int i = t; i < NZERO; i += 256) cnts[i] = 0u;
    }
}

// ---------------------------------------------------------------------------
// sync primitives
// ---------------------------------------------------------------------------
__device__ __forceinline__ unsigned long long flag8_ld(const unsigned char* f) {
    return __hip_atomic_load((const unsigned long long*)f, __ATOMIC_RELAXED,
                             __HIP_MEMORY_SCOPE_AGENT);
}
__device__ __forceinline__ void flag_st(unsigned char* f) {
    __hip_atomic_store(f, (unsigned char)1, __ATOMIC_RELAXED,
                       __HIP_MEMORY_SCOPE_AGENT);
}
__device__ __forceinline__ float ldf_agent(const float* p) {
    return __hip_atomic_load(p, __ATOMIC_RELAXED, __HIP_MEMORY_SCOPE_AGENT);
}
__device__ __forceinline__ void store_wt(float* p, float v) {
    __hip_atomic_store(p, v, __ATOMIC_RELAXED, __HIP_MEMORY_SCOPE_AGENT);
}

// one window pixel for 8 channels (this wave's seq); E = exp(U) input
__device__ __forceinline__ void pix(const float4 E0, const float4 E1,
                                    const float* ar, const float* er, float* hacc) {
    float ee[8] = {E0.x,E0.y,E0.z,E0.w,E1.x,E1.y,E1.z,E1.w};
    float ds = 0.f, tl[8];
    #pragma unroll
    for (int j = 0; j < 8; ++j) {
        float sv = ar[j] + __logf(ee[j]);
        float pv = er[j] * ee[j];
        ds += fmaxf(pv, 1.0f);
        tl[j] = fmaxf(sv, 0.0f) * pv;
    }
    #pragma unroll
    for (int off = 32; off; off >>= 1) ds += __shfl_xor(ds, off, 64);
    float rd = 1.0f / ds;
    #pragma unroll
    for (int j = 0; j < 8; ++j) hacc[j] += tl[j] * rd;
}

// process n pixels at rowp + y*CC, 4-deep pipelined plain loads
__device__ __forceinline__ void proc_row(const float* __restrict__ rowp, int n,
                                         const float* ar, const float* er, float* hacc) {
    float4 cur[4][2];
    int y = 0, curn = (n < 4) ? n : 4;
    #pragma unroll
    for (int i = 0; i < 4; ++i) if (i < curn) {
        cur[i][0] = *(const float4*)(rowp + (size_t)i * CC);
        cur[i][1] = *(const float4*)(rowp + (size_t)i * CC + 256);
    }
    while (true) {
        int yn = y + curn;
        int rem = n - yn;
        int nextn = (rem < 4) ? rem : 4;
        float4 nxt[4][2];
        #pragma unroll
        for (int i = 0; i < 4; ++i) if (i < nextn) {
            nxt[i][0] = *(const float4*)(rowp + (size_t)(yn + i) * CC);
            nxt[i][1] = *(const float4*)(rowp + (size_t)(yn + i) * CC + 256);
        }
        #pragma unroll
        for (int i = 0; i < 4; ++i) if (i < curn)
            pix(cur[i][0], cur[i][1], ar, er, hacc);
        if (nextn <= 0) break;
        #pragma unroll
        for (int i = 0; i < 4; ++i) if (i < nextn) {
            cur[i][0] = nxt[i][0]; cur[i][1] = nxt[i][1];
        }
        curn = nextn; y = yn;
    }
}

// ---------------------------------------------------------------------------
// One kernel, two roles:
//   blockIdx 0..111   : row workers (row=bid>>3, 64-ch slice).
//     Round 4: byte-flag publish (no same-line atomicAdd RMW chain -- the
//     consumer observed the LAST of 8 serialized MALL RMWs; now producers
//     store independent bytes and consumers poll one 8B load). Also removed
//     the post-hT8 __syncthreads: wave wv's matvec stripe hT8[wv*512..+512)
//     is written exactly by wave wv's own threads (same-wave LDS ordering),
//     so each wave starts its matvec as soon as ITS OWN loads land.
//   blockIdx 112..307 : per-cell bulk WGs, chunked rows (round 3), byte-flag
//     gates + byte-flag h publish (round 4).
// ---------------------------------------------------------------------------
__global__ __launch_bounds__(512, 2) void rnn_dataflow(
    const float* __restrict__ A, const float* __restrict__ WhT,
    float* __restrict__ E, float* __restrict__ h_bulk,
    float* __restrict__ h_t, float* __restrict__ TLN,
    float* __restrict__ TLW, float* __restrict__ dsAcc,
    unsigned char* __restrict__ uflag, unsigned char* __restrict__ hflag) {
    __shared__ __align__(16) float hT8[CC * 8];   // full h [k][s], stride 8
    __shared__ __align__(16) float up[8 * 576];   // matvec partials [wave][c*9+s]
    __shared__ unsigned mbox;                     // bulk WG: ready-chunks bitmap
    int bid = blockIdx.x;
    int t = threadIdx.x;
    int lane = t & 63, wv = t >> 6;

    if (bid < NWORK) {
        // ================= row worker =================
        int px = bid >> 3, w = bid & 7;
        int ch = w * 64 + lane;                   // this thread's publish channel
        int m = wv >> 1, b = wv & 1;              // seq decode (s = wv)
        float wreg2[64];                          // WhT[64wv+kk][ch]
        #pragma unroll
        for (int kk = 0; kk < 64; ++kk)
            wreg2[kk] = WhT[(size_t)(wv * 64 + kk) * CC + ch];
        __builtin_amdgcn_s_setprio(1);

        for (int py = 0; py < WW; ++py) {
            int cell = px * WW + py;
            int cellN = cell - WW, cellW = cell - 1;

            // prefetch consumer-cell a values (overlaps the polls)
            float aSr = 0.f, aWr = 0.f;
            if (px < HH - 1) {
                int fi = (m & 2) ? (HH - 2 - px) : (px + 1);
                int fj = (m & 1) ? (WW - 1 - py) : py;
                aSr = A[((size_t)b * PP + fi * WW + fj) * CC + ch];
            }
            if (py < WW - 1) {
                int fi = (m & 2) ? (HH - 1 - px) : px;
                int fj = (m & 1) ? (WW - 2 - py) : (py + 1);
                aWr = A[((size_t)b * PP + fi * WW + fj) * CC + ch];
            }

            // phase 1: bulk h ready? (chunked bulk publishes with slack)
            if (wv == 0 && lane == 0)
                while (flag8_ld(hflag + (size_t)cell * 64) != ALL8)
                    __builtin_amdgcn_s_sleep(1);
            __syncthreads();
            asm volatile("" ::: "memory");
            float hb[8];
            #pragma unroll
            for (int s = 0; s < 8; ++s)
                hb[s] = h_bulk[((size_t)cell * NSEQ + s) * CC + t];

            // phase 2: N/W publishes ready? (hb loads in flight during wait)
            if (wv == 0) {
                while (true) {
                    unsigned ok = 1u;
                    if (lane == 0)      { if (px > 0) ok = (flag8_ld(uflag + (size_t)cellN * 64) == ALL8); }
                    else if (lane == 1) { if (py > 0) ok = (flag8_ld(uflag + (size_t)cellW * 64) == ALL8); }
                    if (__ballot(ok != 0u) == ~0ull) break;
                    __builtin_amdgcn_s_sleep(1);
                }
            }
            __syncthreads();
            asm volatile("" ::: "memory");

            // stage producer-precomputed tails (channel = t) into hb
            float ds16[16];
            if (px > 0) {
                #pragma unroll
                for (int i = 0; i < 8; ++i)
                    ds16[i] = ldf_agent(&dsAcc[(size_t)cell * 16 + i]);
            }
            if (py > 0) {
                #pragma unroll
                for (int i = 8; i < 16; ++i)
                    ds16[i] = ldf_agent(&dsAcc[(size_t)cell * 16 + i]);
            }
            if (px > 0) {
                #pragma unroll
                for (int s = 0; s < 8; ++s)
                    hb[s] += ldf_agent(&TLN[((size_t)cell * NSEQ + s) * CC + t])
                             * __builtin_amdgcn_rcpf(ds16[s]);
            }
            if (py > 0) {
                #pragma unroll
                for (int s = 0; s < 8; ++s)
                    hb[s] += ldf_agent(&TLW[((size_t)cell * NSEQ + s) * CC + t])
                             * __builtin_amdgcn_rcpf(ds16[8 + s]);
            }
            if ((t >> 6) == w) {   // h_t: this slice's own 64-ch stripe only
                #pragma unroll
                for (int s = 0; s < 8; ++s)
                    h_t[((size_t)cell * NSEQ + s) * CC + t] = hb[s];
            }
            *(float4*)&hT8[t * 8]     = make_float4(hb[0], hb[1], hb[2], hb[3]);
            *(float4*)&hT8[t * 8 + 4] = make_float4(hb[4], hb[5], hb[6], hb[7]);
            // NO barrier: wave wv's matvec reads exactly its own threads' hT8
            // stripe (same-wave LDS ordering). Waves de-lockstep here.
            if (cell == PP - 1) break;           // (13,13): no U consumer

            // matvec: wave wv owns k in [64wv, 64wv+64); lane owns channel.
            // hT8 reads are wave-uniform b128 (LDS broadcast, conflict-free).
            float acc[8] = {0.f,0.f,0.f,0.f,0.f,0.f,0.f,0.f};
            const float* hp = hT8 + (wv << 9);
            #pragma unroll
            for (int kk = 0; kk < 64; ++kk) {
                float4 h0 = *(const float4*)(hp + kk * 8);
                float4 h1 = *(const float4*)(hp + kk * 8 + 4);
                float wvv = wreg2[kk];
                acc[0] += wvv * h0.x; acc[1] += wvv * h0.y;
                acc[2] += wvv * h0.z; acc[3] += wvv * h0.w;
                acc[4] += wvv * h1.x; acc[5] += wvv * h1.y;
                acc[6] += wvv * h1.z; acc[7] += wvv * h1.w;
            }
            #pragma unroll
            for (int s = 0; s < 8; ++s)
                up[wv * 576 + lane * 9 + s] = acc[s];   // full overwrite, no zeroing
            __syncthreads();

            // publish: U, E = exp(U), consumer tails + denominator partials
            {
                float U = up[lane * 9 + wv];
                #pragma unroll
                for (int w2 = 1; w2 < 8; ++w2) U += up[w2 * 576 + lane * 9 + wv];
                float Ev = __expf(U);
                store_wt(&E[((size_t)wv * PP + cell) * CC + ch], Ev);
                float pdS = 0.f, pdW = 0.f;
                if (px < HH - 1) {
                    float pv = __expf(aSr) * Ev;
                    store_wt(&TLN[((size_t)(cell + WW) * NSEQ + wv) * CC + ch],
                             fmaxf(aSr + U, 0.f) * pv);
                    pdS = fmaxf(pv, 1.f);
                }
                if (py < WW - 1) {
                    float pv = __expf(aWr) * Ev;
                    store_wt(&TLW[((size_t)(cell + 1) * NSEQ + wv) * CC + ch],
                             fmaxf(aWr + U, 0.f) * pv);
                    pdW = fmaxf(pv, 1.f);
                }
                #pragma unroll
                for (int off = 32; off; off >>= 1) {
                    pdS += __shfl_xor(pdS, off, 64);
                    pdW += __shfl_xor(pdW, off, 64);
                }
                if (lane == 0) {
                    if (px < HH - 1)
                        unsafeAtomicAdd(&dsAcc[(size_t)(cell + WW) * 16 + wv], pdS);
                    if (py < WW - 1)
                        unsafeAtomicAdd(&dsAcc[(size_t)(cell + 1) * 16 + 8 + wv], pdW);
                }
            }
            __syncthreads();     // all waves' stores/atomics drained (vmcnt 0 @ barrier)
            if (t == 0) flag_st(uflag + (size_t)cell * 64 + w);   // byte, no RMW
        }
    } else {
        // ================= bulk window WG (chunked rows), off-path ==========
        int cell = bid - NWORK;
        int px = cell / WW, py = cell % WW;
        int s = wv, m = s >> 1, b = s & 1;
        int fi = (m & 2) ? (HH-1-px) : px;
        int fj = (m & 1) ? (WW-1-py) : py;
        int cb = lane * 4;

        if (t == 0) mbox = 0u;
        __syncthreads();          // once, at WG start (long before deps ready)

        const float* acur = A + ((size_t)b * PP + fi * WW + fj) * CC;
        float4 a0 = *(const float4*)(acur + cb);
        float4 a1 = *(const float4*)(acur + cb + 256);
        float ar[8] = {a0.x,a0.y,a0.z,a0.w,a1.x,a1.y,a1.z,a1.w};
        float er[8];
        #pragma unroll
        for (int j = 0; j < 8; ++j) er[j] = __expf(ar[j]);
        float hacc[8] = {0.f,0.f,0.f,0.f,0.f,0.f,0.f,0.f};

        {   // self pixel first (needs no U at all): U=0 -> E=1
            float ds = 0.f, tl[8];
            #pragma unroll
            for (int j = 0; j < 8; ++j) {
                float pv = er[j];
                ds += fmaxf(pv, 1.0f);
                tl[j] = fmaxf(ar[j], 0.0f) * pv;
            }
            #pragma unroll
            for (int off = 32; off; off >>= 1) ds += __shfl_xor(ds, off, 64);
            float rd = 1.0f / ds;
            #pragma unroll
            for (int j = 0; j < 8; ++j) hacc[j] += tl[j] * rd;
        }

        const float* Eb = E + (size_t)s * PP * CC;
        // chunk slots: slot = lane, row x = lane>>1, phase = lane&1.
        // row limit L: x<=px-2 -> py ; x=px-1 -> py-1 ; x=px -> py-2
        //   L<=2 : single chunk [0..L]    gate (x,L)     at slot (2x+0)
        //   L>2  : early [0..L-3]         gate (x,L-3)   at slot (2x+0)
        //          late  [L-2..L] (3 px)  gate (x,L)     at slot (2x+1)
        int sx = lane >> 1, sph = lane & 1;
        int gate = -1;
        if (sx <= px) {
            int L = (sx <= px-2) ? py : ((sx == px-1) ? py-1 : py-2);
            if (L >= 0) {
                if (L <= 2) { if (sph == 0) gate = sx * WW + L; }
                else gate = sx * WW + (sph ? L : (L - 3));
            }
        }
        unsigned pend = (unsigned)__ballot(gate >= 0);

        if (wv == 0) {
            // sole fabric poller: lane l checks its chunk's gate flags (1 load)
            unsigned done = 0u;
            while (pend) {
                bool rdy = true;
                if (gate >= 0 && ((pend >> lane) & 1u))
                    rdy = (flag8_ld(uflag + (size_t)gate * 64) == ALL8);
                unsigned newly = pend & (unsigned)__ballot(rdy);
                if (!newly) { __builtin_amdgcn_s_sleep(2); continue; }
                done |= newly;
                __hip_atomic_store(&mbox, done, __ATOMIC_RELAXED,
                                   __HIP_MEMORY_SCOPE_WORKGROUP);
                asm volatile("" ::: "memory");
                unsigned go = newly;
                while (go) {
                    int sl = __ffs(go) - 1; go &= go - 1;
                    int xx = sl >> 1;
                    int L = (xx <= px-2) ? py : ((xx == px-1) ? py-1 : py-2);
                    int yy0 = 0, yy1 = L;
                    if (L > 2) { if (sl & 1) yy0 = L - 2; else yy1 = L - 3; }
                    proc_row(Eb + (size_t)(xx * WW + yy0) * CC + cb,
                             yy1 - yy0 + 1, ar, er, hacc);
                }
                pend &= ~newly;
            }
        } else {
            while (pend) {
                unsigned d = __hip_atomic_load(&mbox, __ATOMIC_RELAXED,
                                               __HIP_MEMORY_SCOPE_WORKGROUP);
                unsigned newly = d & pend;
                if (!newly) { __builtin_amdgcn_s_sleep(2); continue; }
                asm volatile("" ::: "memory");
                unsigned go = newly;
                while (go) {
                    int sl = __ffs(go) - 1; go &= go - 1;
                    int xx = sl >> 1;
                    int L = (xx <= px-2) ? py : ((xx == px-1) ? py-1 : py-2);
                    int yy0 = 0, yy1 = L;
                    if (L > 2) { if (sl & 1) yy0 = L - 2; else yy1 = L - 3; }
                    proc_row(Eb + (size_t)(xx * WW + yy0) * CC + cb,
                             yy1 - yy0 + 1, ar, er, hacc);
                }
                pend &= ~newly;
            }
        }

        // per-wave publish h_bulk: contiguous WT stores + drain + byte flag
        float* hp = h_bulk + ((size_t)cell * NSEQ + s) * CC;
        #pragma unroll
        for (int j = 0; j < 4; ++j) {
            store_wt(hp + cb + j,       hacc[j]);
            store_wt(hp + cb + 256 + j, hacc[4 + j]);
        }
        __builtin_amdgcn_s_waitcnt(0);
        asm volatile("" ::: "memory");
        if (lane == 0) flag_st(hflag + (size_t)cell * 64 + s);
    }
}

// ---------------------------------------------------------------------------
// gemm_y: Y[b][p][c] = sum_k Wo[c][k] * (sum_m h_t[p][2m+b][k]) + 4*b_out[c]
// ---------------------------------------------------------------------------
__global__ __launch_bounds__(256) void gemm_y(
    const float* __restrict__ Wo, const float* __restrict__ h_t,
    const float* __restrict__ b_out, float* __restrict__ Y) {
    __shared__ float Ws[32][33], Hs[32][33];
    int b  = blockIdx.z;
    int c0 = blockIdx.x * 32, p0 = blockIdx.y * 32;
    int t  = threadIdx.x;
    int tx = t % 32, ty = t / 32;
    int pl = (t % 16) * 2, cl = (t / 16) * 2;
    float acc[2][2] = {{0.f,0.f},{0.f,0.f}};
    for (int k0 = 0; k0 < CC; k0 += 32) {
        #pragma unroll
        for (int r = 0; r < 4; ++r)
            Ws[ty + 8*r][tx] = Wo[(size_t)(c0 + ty + 8*r) * CC + k0 + tx];
        #pragma unroll
        for (int r = 0; r < 4; ++r) {
            int p = p0 + ty + 8*r;
            float v = 0.f;
            if (p < PP) {
                size_t base = (size_t)p * NSEQ * CC + k0 + tx;
                v = h_t[base + (size_t)(0 + b) * CC]
                  + h_t[base + (size_t)(2 + b) * CC]
                  + h_t[base + (size_t)(4 + b) * CC]
                  + h_t[base + (size_t)(6 + b) * CC];
            }
            Hs[tx][ty + 8*r] = v;
        }
        __syncthreads();
        #pragma unroll
        for (int k = 0; k < 32; ++k) {
            float w0 = Ws[cl][k], w1 = Ws[cl+1][k];
            float h0 = Hs[k][pl], h1 = Hs[k][pl+1];
            acc[0][0] += w0*h0; acc[0][1] += w0*h1;
            acc[1][0] += w1*h0; acc[1][1] += w1*h1;
        }
        __syncthreads();
    }
    #pragma unroll
    for (int i = 0; i < 2; ++i)
        #pragma unroll
        for (int j = 0; j < 2; ++j) {
            int cc = c0 + cl + i, p = p0 + pl + j;
            if (p < PP) Y[((size_t)b * PP + p) * CC + cc] = acc[i][j] + 4.0f * b_out[cc];
        }
}

// ---------------------------------------------------------------------------
// softmax over channels -> out[b][c][p]
// ---------------------------------------------------------------------------
__global__ __launch_bounds__(256) void softmax_out(
    const float* __restrict__ Y, float* __restrict__ out) {
    int wave = threadIdx.x >> 6, lane = threadIdx.x & 63;
    int idx = blockIdx.x * 4 + wave;
    if (idx >= BB * PP) return;
    int b = idx / PP, p = idx % PP;
    const float* y = Y + ((size_t)b * PP + p) * CC;
    float v[8];
    float mx = -3.4e38f;
    #pragma unroll
    for (int j = 0; j < 8; ++j) { v[j] = y[lane + 64*j]; mx = fmaxf(mx, v[j]); }
    #pragma unroll
    for (int off = 32; off; off >>= 1) mx = fmaxf(mx, __shfl_xor(mx, off, 64));
    float sum = 0.f;
    #pragma unroll
    for (int j = 0; j < 8; ++j) { v[j] = expf(v[j] - mx); sum += v[j]; }
    #pragma unroll
    for (int off = 32; off; off >>= 1) sum += __shfl_xor(sum, off, 64);
    float r = 1.0f / sum;
    #pragma unroll
    for (int j = 0; j < 8; ++j)
        out[((size_t)b * CC + lane + 64*j) * PP + p] = v[j] * r;
}

// ---------------------------------------------------------------------------
extern "C" void kernel_launch(void* const* d_in, const int* in_sizes, int n_in,
                              void* d_out, int out_size, void* d_ws, size_t ws_size,
                              hipStream_t stream) {
    const float* X     = (const float*)d_in[0];
    const float* Wx    = (const float*)d_in[1];
    const float* Wh    = (const float*)d_in[2];
    const float* b_in  = (const float*)d_in[3];
    const float* Wo    = (const float*)d_in[4];
    const float* b_out = (const float*)d_in[5];
    float* out = (float*)d_out;

    float* ws     = (float*)d_ws;
    float* WhT    = ws;                     // 262144
    float* A      = WhT    + 262144;        // 200704
    float* E      = A      + 200704;        // 802816  [s][cell][c] = exp(U)
    float* h_bulk = E      + 802816;        // 802816  [cell][s][c]
    float* h_t    = h_bulk + 802816;        // 802816  [cell][s][c] full h
    float* TLN    = h_t    + 802816;        // 802816  [cell][s][c] tail from North
    float* TLW    = TLN    + 802816;        // 802816  [cell][s][c] tail from West
    float* Y      = TLW    + 802816;        // 200704
    unsigned char* uflag = (unsigned char*)(Y + 200704);   // PP*64 B
    unsigned char* hflag = uflag + PP * 64;                // PP*64 B
    float* dsAcc = (float*)(hflag + PP * 64);              // PP*16: [cell][N|W]

    hipLaunchKernelGGL(prep, dim3(481), dim3(256), 0, stream,
                       Wx, X, b_in, Wh, A, WhT, (unsigned*)uflag);
    hipLaunchKernelGGL(rnn_dataflow, dim3(NWORK + PP), dim3(512), 0, stream,
                       A, WhT, E, h_bulk, h_t, TLN, TLW, dsAcc, uflag, hflag);
    hipLaunchKernelGGL(gemm_y, dim3(16, 7, 2), dim3(256), 0, stream, Wo, h_t, b_out, Y);
    hipLaunchKernelGGL(softmax_out, dim3(98), dim3(256), 0, stream, Y, out);
}

// Round 6
// 353.547 us; speedup vs baseline: 1.5239x; 1.0221x over previous
//
#include <hip/hip_runtime.h>
#include <hip/hip_bf16.h>

#define BB 2
#define CC 512
#define HH 14
#define WW 14
#define PP 196
#define NSEQ 8
#define NSLICE 8                 // worker WGs per row (64 ch each)
#define NWORK (14 * NSLICE)      // 112
#define FW 16                    // dwords per flag/ds line (64B)
#define NZERO (3 * PP * FW)      // uflag + hflag + dsAcc (all zeroed)
#define ALL8 0x0101010101010101ull

// flags: uflag[cell*64 + w] = 1 byte per slice publish (8 bytes == E/TL/ds ready)
//        hflag[cell*64 + s] = 1 byte per bulk-wave publish (8 bytes == h_bulk ready)

// ---------------------------------------------------------------------------
// prep: gemm_a (224 WGs) + transpose_wh (256 WGs) + flag/dsAcc zero (1 WG)
// ---------------------------------------------------------------------------
__global__ __launch_bounds__(256) void prep(
    const float* __restrict__ Wx, const float* __restrict__ X,
    const float* __restrict__ b_in, const float* __restrict__ Wh,
    float* __restrict__ A, float* __restrict__ WhT,
    unsigned* __restrict__ cnts /* uflag, hflag, dsAcc contiguous */) {
    __shared__ float Ws[32][33], Xs[32][33];
    int bid = blockIdx.x;
    int t = threadIdx.x;
    if (bid < 224) {
        int z = bid / 112, rem = bid % 112;
        int c0 = (rem % 16) * 32, p0 = (rem / 16) * 32;
        int tx = t % 32, ty = t / 32;
        int pl = (t % 16) * 2, cl = (t / 16) * 2;
        float acc[2][2] = {{0.f,0.f},{0.f,0.f}};
        for (int k0 = 0; k0 < CC; k0 += 32) {
            #pragma unroll
            for (int r = 0; r < 4; ++r)
                Ws[ty + 8*r][tx] = Wx[(size_t)(c0 + ty + 8*r) * CC + k0 + tx];
            #pragma unroll
            for (int r = 0; r < 4; ++r) {
                int p = p0 + tx, k = k0 + ty + 8*r;
                Xs[ty + 8*r][tx] = (p < PP) ? X[((size_t)z * CC + k) * PP + p] : 0.f;
            }
            __syncthreads();
            #pragma unroll
            for (int k = 0; k < 32; ++k) {
                float w0 = Ws[cl][k], w1 = Ws[cl+1][k];
                float x0 = Xs[k][pl], x1 = Xs[k][pl+1];
                acc[0][0] += w0*x0; acc[0][1] += w0*x1;
                acc[1][0] += w1*x0; acc[1][1] += w1*x1;
            }
            __syncthreads();
        }
        #pragma unroll
        for (int i = 0; i < 2; ++i)
            #pragma unroll
            for (int j = 0; j < 2; ++j) {
                int c = c0 + cl + i, p = p0 + pl + j;
                if (p < PP) A[((size_t)z * PP + p) * CC + c] = acc[i][j] + b_in[c];
            }
    } else if (bid < 480) {
        int tid = bid - 224;
        int c0 = (tid % 16) * 32, k0 = (tid / 16) * 32;
        int tx = t % 32, ty = t / 32;
        #pragma unroll
        for (int r = 0; r < 4; ++r)
            Ws[ty + 8*r][tx] = Wh[(size_t)(c0 + ty + 8*r) * CC + k0 + tx];
        __syncthreads();
        #pragma unroll
        for (int r = 0; r < 4; ++r)
            WhT[(size_t)(k0 + ty + 8*r) * CC + c0 + tx] = Ws[tx][ty + 8*r];
    } else {
        for (int i = t; i < NZERO; i += 256) cnts[i] = 0u;
    }
}

// ---------------------------------------------------------------------------
// sync primitives
// ---------------------------------------------------------------------------
__device__ __forceinline__ unsigned long long flag8_ld(const unsigned char* f) {
    return __hip_atomic_load((const unsigned long long*)f, __ATOMIC_RELAXED,
                             __HIP_MEMORY_SCOPE_AGENT);
}
__device__ __forceinline__ void flag_st(unsigned char* f) {
    __hip_atomic_store(f, (unsigned char)1, __ATOMIC_RELAXED,
                       __HIP_MEMORY_SCOPE_AGENT);
}
__device__ __forceinline__ float ldf_agent(const float* p) {
    return __hip_atomic_load(p, __ATOMIC_RELAXED, __HIP_MEMORY_SCOPE_AGENT);
}
__device__ __forceinline__ void store_wt(float* p, float v) {
    __hip_atomic_store(p, v, __ATOMIC_RELAXED, __HIP_MEMORY_SCOPE_AGENT);
}

// one window pixel for 8 channels (this wave's seq); E = exp(U) input
__device__ __forceinline__ void pix(const float4 E0, const float4 E1,
                                    const float* ar, const float* er, float* hacc) {
    float ee[8] = {E0.x,E0.y,E0.z,E0.w,E1.x,E1.y,E1.z,E1.w};
    float ds = 0.f, tl[8];
    #pragma unroll
    for (int j = 0; j < 8; ++j) {
        float sv = ar[j] + __logf(ee[j]);
        float pv = er[j] * ee[j];
        ds += fmaxf(pv, 1.0f);
        tl[j] = fmaxf(sv, 0.0f) * pv;
    }
    #pragma unroll
    for (int off = 32; off; off >>= 1) ds += __shfl_xor(ds, off, 64);
    float rd = 1.0f / ds;
    #pragma unroll
    for (int j = 0; j < 8; ++j) hacc[j] += tl[j] * rd;
}

// process n pixels at rowp + y*CC, 4-deep pipelined plain loads
__device__ __forceinline__ void proc_row(const float* __restrict__ rowp, int n,
                                         const float* ar, const float* er, float* hacc) {
    float4 cur[4][2];
    int y = 0, curn = (n < 4) ? n : 4;
    #pragma unroll
    for (int i = 0; i < 4; ++i) if (i < curn) {
        cur[i][0] = *(const float4*)(rowp + (size_t)i * CC);
        cur[i][1] = *(const float4*)(rowp + (size_t)i * CC + 256);
    }
    while (true) {
        int yn = y + curn;
        int rem = n - yn;
        int nextn = (rem < 4) ? rem : 4;
        float4 nxt[4][2];
        #pragma unroll
        for (int i = 0; i < 4; ++i) if (i < nextn) {
            nxt[i][0] = *(const float4*)(rowp + (size_t)(yn + i) * CC);
            nxt[i][1] = *(const float4*)(rowp + (size_t)(yn + i) * CC + 256);
        }
        #pragma unroll
        for (int i = 0; i < 4; ++i) if (i < curn)
            pix(cur[i][0], cur[i][1], ar, er, hacc);
        if (nextn <= 0) break;
        #pragma unroll
        for (int i = 0; i < 4; ++i) if (i < nextn) {
            cur[i][0] = nxt[i][0]; cur[i][1] = nxt[i][1];
        }
        curn = nextn; y = yn;
    }
}

// ---------------------------------------------------------------------------
// One kernel, two roles:
//   blockIdx 0..111   : row workers (row=bid>>3, 64-ch slice).
//     Round 6 (fixes round-5 NaN): h_bulk(cell+1) prefetch decision is made
//     WORKGROUP-UNIFORM -- t==0 reads hflag(cell+1) before the publish drain
//     barrier and posts the verdict to LDS; after the barrier all threads see
//     the same hb_ok, so the phase-1 fallback (which contains __syncthreads)
//     can never diverge. Round 5's per-thread flag reads gave threads
//     different hb_ok -> mismatched barrier counts -> sheared pipeline -> NaN.
//     Prefetched loads issue right after the drain barrier; their latency
//     overlaps flag_st + next cell's A-prefetch + the N/W observe leg.
//   blockIdx 112..307 : per-cell bulk WGs, chunked rows, byte-flag gates.
// ---------------------------------------------------------------------------
__global__ __launch_bounds__(512, 2) void rnn_dataflow(
    const float* __restrict__ A, const float* __restrict__ WhT,
    float* __restrict__ E, float* __restrict__ h_bulk,
    float* __restrict__ h_t, float* __restrict__ TLN,
    float* __restrict__ TLW, float* __restrict__ dsAcc,
    unsigned char* __restrict__ uflag, unsigned char* __restrict__ hflag) {
    __shared__ __align__(16) float hT8[CC * 8];   // full h [k][s], stride 8
    __shared__ __align__(16) float up[8 * 576];   // matvec partials [wave][c*9+s]
    __shared__ unsigned mbox;                     // bulk WG: ready-chunks bitmap
    __shared__ unsigned pf;                       // worker: uniform prefetch verdict
    int bid = blockIdx.x;
    int t = threadIdx.x;
    int lane = t & 63, wv = t >> 6;

    if (bid < NWORK) {
        // ================= row worker =================
        int px = bid >> 3, w = bid & 7;
        int ch = w * 64 + lane;                   // this thread's publish channel
        int m = wv >> 1, b = wv & 1;              // seq decode (s = wv)
        float wreg2[64];                          // WhT[64wv+kk][ch]
        #pragma unroll
        for (int kk = 0; kk < 64; ++kk)
            wreg2[kk] = WhT[(size_t)(wv * 64 + kk) * CC + ch];
        __builtin_amdgcn_s_setprio(1);

        float hb[8];
        bool hb_ok = false;       // hb[] prefetched for the upcoming cell? (uniform)

        for (int py = 0; py < WW; ++py) {
            int cell = px * WW + py;
            int cellN = cell - WW, cellW = cell - 1;

            // prefetch consumer-cell a values (overlaps the polls)
            float aSr = 0.f, aWr = 0.f;
            if (px < HH - 1) {
                int fi = (m & 2) ? (HH - 2 - px) : (px + 1);
                int fj = (m & 1) ? (WW - 1 - py) : py;
                aSr = A[((size_t)b * PP + fi * WW + fj) * CC + ch];
            }
            if (py < WW - 1) {
                int fi = (m & 2) ? (HH - 1 - px) : px;
                int fj = (m & 1) ? (WW - 2 - py) : (py + 1);
                aWr = A[((size_t)b * PP + fi * WW + fj) * CC + ch];
            }

            // phase 1 (fallback only, hb_ok is workgroup-uniform): observe + load
            if (!hb_ok) {
                if (wv == 0 && lane == 0)
                    while (flag8_ld(hflag + (size_t)cell * 64) != ALL8)
                        __builtin_amdgcn_s_sleep(1);
                __syncthreads();
                asm volatile("" ::: "memory");
                #pragma unroll
                for (int s = 0; s < 8; ++s)
                    hb[s] = h_bulk[((size_t)cell * NSEQ + s) * CC + t];
            }

            // phase 2: N/W publishes ready? (hb loads in flight during wait)
            if (wv == 0) {
                while (true) {
                    unsigned ok = 1u;
                    if (lane == 0)      { if (px > 0) ok = (flag8_ld(uflag + (size_t)cellN * 64) == ALL8); }
                    else if (lane == 1) { if (py > 0) ok = (flag8_ld(uflag + (size_t)cellW * 64) == ALL8); }
                    if (__ballot(ok != 0u) == ~0ull) break;
                    __builtin_amdgcn_s_sleep(1);
                }
            }
            __syncthreads();
            asm volatile("" ::: "memory");

            // ONE batched load leg: ds16 + TLN + TLW together
            float ds16[16], tn[8], tw[8];
            if (px > 0) {
                #pragma unroll
                for (int i = 0; i < 8; ++i)
                    ds16[i] = ldf_agent(&dsAcc[(size_t)cell * 16 + i]);
                #pragma unroll
                for (int s = 0; s < 8; ++s)
                    tn[s] = ldf_agent(&TLN[((size_t)cell * NSEQ + s) * CC + t]);
            }
            if (py > 0) {
                #pragma unroll
                for (int i = 8; i < 16; ++i)
                    ds16[i] = ldf_agent(&dsAcc[(size_t)cell * 16 + i]);
                #pragma unroll
                for (int s = 0; s < 8; ++s)
                    tw[s] = ldf_agent(&TLW[((size_t)cell * NSEQ + s) * CC + t]);
            }
            if (px > 0) {
                #pragma unroll
                for (int s = 0; s < 8; ++s)
                    hb[s] += tn[s] * __builtin_amdgcn_rcpf(ds16[s]);
            }
            if (py > 0) {
                #pragma unroll
                for (int s = 0; s < 8; ++s)
                    hb[s] += tw[s] * __builtin_amdgcn_rcpf(ds16[8 + s]);
            }
            if (wv == w) {   // h_t: this slice's own 64-ch stripe only
                #pragma unroll
                for (int s = 0; s < 8; ++s)
                    h_t[((size_t)cell * NSEQ + s) * CC + t] = hb[s];
            }
            *(float4*)&hT8[t * 8]     = make_float4(hb[0], hb[1], hb[2], hb[3]);
            *(float4*)&hT8[t * 8 + 4] = make_float4(hb[4], hb[5], hb[6], hb[7]);
            // no barrier: wave wv's matvec reads exactly its own threads' stripe
            if (cell == PP - 1) break;           // (13,13): no U consumer

            // matvec: wave wv owns k in [64wv, 64wv+64); lane owns channel.
            float acc[8] = {0.f,0.f,0.f,0.f,0.f,0.f,0.f,0.f};
            const float* hp = hT8 + (wv << 9);
            #pragma unroll
            for (int kk = 0; kk < 64; ++kk) {
                float4 h0 = *(const float4*)(hp + kk * 8);
                float4 h1 = *(const float4*)(hp + kk * 8 + 4);
                float wvv = wreg2[kk];
                acc[0] += wvv * h0.x; acc[1] += wvv * h0.y;
                acc[2] += wvv * h0.z; acc[3] += wvv * h0.w;
                acc[4] += wvv * h1.x; acc[5] += wvv * h1.y;
                acc[6] += wvv * h1.z; acc[7] += wvv * h1.w;
            }
            #pragma unroll
            for (int s = 0; s < 8; ++s)
                up[wv * 576 + lane * 9 + s] = acc[s];   // full overwrite, no zeroing
            __syncthreads();

            // publish: U, E = exp(U), consumer tails + denominator partials
            {
                float U = up[lane * 9 + wv];
                #pragma unroll
                for (int w2 = 1; w2 < 8; ++w2) U += up[w2 * 576 + lane * 9 + wv];
                float Ev = __expf(U);
                store_wt(&E[((size_t)wv * PP + cell) * CC + ch], Ev);
                float pdS = 0.f, pdW = 0.f;
                if (px < HH - 1) {
                    float pv = __expf(aSr) * Ev;
                    store_wt(&TLN[((size_t)(cell + WW) * NSEQ + wv) * CC + ch],
                             fmaxf(aSr + U, 0.f) * pv);
                    pdS = fmaxf(pv, 1.f);
                }
                if (py < WW - 1) {
                    float pv = __expf(aWr) * Ev;
                    store_wt(&TLW[((size_t)(cell + 1) * NSEQ + wv) * CC + ch],
                             fmaxf(aWr + U, 0.f) * pv);
                    pdW = fmaxf(pv, 1.f);
                }
                #pragma unroll
                for (int off = 32; off; off >>= 1) {
                    pdS += __shfl_xor(pdS, off, 64);
                    pdW += __shfl_xor(pdW, off, 64);
                }
                if (lane == 0) {
                    if (px < HH - 1)
                        unsafeAtomicAdd(&dsAcc[(size_t)(cell + WW) * 16 + wv], pdS);
                    if (py < WW - 1)
                        unsafeAtomicAdd(&dsAcc[(size_t)(cell + 1) * 16 + 8 + wv], pdW);
                }
            }

            // uniform prefetch verdict for cell+1: ONE reader, LDS broadcast.
            // (Round-5 bug: per-thread flag reads -> divergent hb_ok -> the
            //  phase-1 fallback __syncthreads mismatched across waves -> NaN.)
            if (t == 0)
                pf = (py + 1 < WW &&
                      flag8_ld(hflag + (size_t)(cell + 1) * 64) == ALL8) ? 1u : 0u;

            __syncthreads();     // drain: stores/atomics acked; pf visible
            if (t == 0) flag_st(uflag + (size_t)cell * 64 + w);   // byte, no RMW

            hb_ok = false;
            if (py + 1 < WW && pf != 0u) {
                // issue now: latency overlaps flag_st + A-prefetch + N/W poll
                #pragma unroll
                for (int s = 0; s < 8; ++s)
                    hb[s] = h_bulk[((size_t)(cell + 1) * NSEQ + s) * CC + t];
                hb_ok = true;
            }
        }
    } else {
        // ================= bulk window WG (chunked rows), off-path ==========
        int cell = bid - NWORK;
        int px = cell / WW, py = cell % WW;
        int s = wv, m = s >> 1, b = s & 1;
        int fi = (m & 2) ? (HH-1-px) : px;
        int fj = (m & 1) ? (WW-1-py) : py;
        int cb = lane * 4;

        if (t == 0) mbox = 0u;
        __syncthreads();          // once, at WG start (long before deps ready)

        const float* acur = A + ((size_t)b * PP + fi * WW + fj) * CC;
        float4 a0 = *(const float4*)(acur + cb);
        float4 a1 = *(const float4*)(acur + cb + 256);
        float ar[8] = {a0.x,a0.y,a0.z,a0.w,a1.x,a1.y,a1.z,a1.w};
        float er[8];
        #pragma unroll
        for (int j = 0; j < 8; ++j) er[j] = __expf(ar[j]);
        float hacc[8] = {0.f,0.f,0.f,0.f,0.f,0.f,0.f,0.f};

        {   // self pixel first (needs no U at all): U=0 -> E=1
            float ds = 0.f, tl[8];
            #pragma unroll
            for (int j = 0; j < 8; ++j) {
                float pv = er[j];
                ds += fmaxf(pv, 1.0f);
                tl[j] = fmaxf(ar[j], 0.0f) * pv;
            }
            #pragma unroll
            for (int off = 32; off; off >>= 1) ds += __shfl_xor(ds, off, 64);
            float rd = 1.0f / ds;
            #pragma unroll
            for (int j = 0; j < 8; ++j) hacc[j] += tl[j] * rd;
        }

        const float* Eb = E + (size_t)s * PP * CC;
        // chunk slots: slot = lane, row x = lane>>1, phase = lane&1.
        // row limit L: x<=px-2 -> py ; x=px-1 -> py-1 ; x=px -> py-2
        //   L<=2 : single chunk [0..L]    gate (x,L)     at slot (2x+0)
        //   L>2  : early [0..L-3]         gate (x,L-3)   at slot (2x+0)
        //          late  [L-2..L] (3 px)  gate (x,L)     at slot (2x+1)
        int sx = lane >> 1, sph = lane & 1;
        int gate = -1;
        if (sx <= px) {
            int L = (sx <= px-2) ? py : ((sx == px-1) ? py-1 : py-2);
            if (L >= 0) {
                if (L <= 2) { if (sph == 0) gate = sx * WW + L; }
                else gate = sx * WW + (sph ? L : (L - 3));
            }
        }
        unsigned pend = (unsigned)__ballot(gate >= 0);

        if (wv == 0) {
            // sole fabric poller: lane l checks its chunk's gate flags (1 load)
            unsigned done = 0u;
            while (pend) {
                bool rdy = true;
                if (gate >= 0 && ((pend >> lane) & 1u))
                    rdy = (flag8_ld(uflag + (size_t)gate * 64) == ALL8);
                unsigned newly = pend & (unsigned)__ballot(rdy);
                if (!newly) { __builtin_amdgcn_s_sleep(2); continue; }
                done |= newly;
                __hip_atomic_store(&mbox, done, __ATOMIC_RELAXED,
                                   __HIP_MEMORY_SCOPE_WORKGROUP);
                asm volatile("" ::: "memory");
                unsigned go = newly;
                while (go) {
                    int sl = __ffs(go) - 1; go &= go - 1;
                    int xx = sl >> 1;
                    int L = (xx <= px-2) ? py : ((xx == px-1) ? py-1 : py-2);
                    int yy0 = 0, yy1 = L;
                    if (L > 2) { if (sl & 1) yy0 = L - 2; else yy1 = L - 3; }
                    proc_row(Eb + (size_t)(xx * WW + yy0) * CC + cb,
                             yy1 - yy0 + 1, ar, er, hacc);
                }
                pend &= ~newly;
            }
        } else {
            while (pend) {
                unsigned d = __hip_atomic_load(&mbox, __ATOMIC_RELAXED,
                                               __HIP_MEMORY_SCOPE_WORKGROUP);
                unsigned newly = d & pend;
                if (!newly) { __builtin_amdgcn_s_sleep(2); continue; }
                asm volatile("" ::: "memory");
                unsigned go = newly;
                while (go) {
                    int sl = __ffs(go) - 1; go &= go - 1;
                    int xx = sl >> 1;
                    int L = (xx <= px-2) ? py : ((xx == px-1) ? py-1 : py-2);
                    int yy0 = 0, yy1 = L;
                    if (L > 2) { if (sl & 1) yy0 = L - 2; else yy1 = L - 3; }
                    proc_row(Eb + (size_t)(xx * WW + yy0) * CC + cb,
                             yy1 - yy0 + 1, ar, er, hacc);
                }
                pend &= ~newly;
            }
        }

        // per-wave publish h_bulk: contiguous WT stores + drain + byte flag
        float* hp = h_bulk + ((size_t)cell * NSEQ + s) * CC;
        #pragma unroll
        for (int j = 0; j < 4; ++j) {
            store_wt(hp + cb + j,       hacc[j]);
            store_wt(hp + cb + 256 + j, hacc[4 + j]);
        }
        __builtin_amdgcn_s_waitcnt(0);
        asm volatile("" ::: "memory");
        if (lane == 0) flag_st(hflag + (size_t)cell * 64 + s);
    }
}

// ---------------------------------------------------------------------------
// gemm_y: Y[b][p][c] = sum_k Wo[c][k] * (sum_m h_t[p][2m+b][k]) + 4*b_out[c]
// ---------------------------------------------------------------------------
__global__ __launch_bounds__(256) void gemm_y(
    const float* __restrict__ Wo, const float* __restrict__ h_t,
    const float* __restrict__ b_out, float* __restrict__ Y) {
    __shared__ float Ws[32][33], Hs[32][33];
    int b  = blockIdx.z;
    int c0 = blockIdx.x * 32, p0 = blockIdx.y * 32;
    int t  = threadIdx.x;
    int tx = t % 32, ty = t / 32;
    int pl = (t % 16) * 2, cl = (t / 16) * 2;
    float acc[2][2] = {{0.f,0.f},{0.f,0.f}};
    for (int k0 = 0; k0 < CC; k0 += 32) {
        #pragma unroll
        for (int r = 0; r < 4; ++r)
            Ws[ty + 8*r][tx] = Wo[(size_t)(c0 + ty + 8*r) * CC + k0 + tx];
        #pragma unroll
        for (int r = 0; r < 4; ++r) {
            int p = p0 + ty + 8*r;
            float v = 0.f;
            if (p < PP) {
                size_t base = (size_t)p * NSEQ * CC + k0 + tx;
                v = h_t[base + (size_t)(0 + b) * CC]
                  + h_t[base + (size_t)(2 + b) * CC]
                  + h_t[base + (size_t)(4 + b) * CC]
                  + h_t[base + (size_t)(6 + b) * CC];
            }
            Hs[tx][ty + 8*r] = v;
        }
        __syncthreads();
        #pragma unroll
        for (int k = 0; k < 32; ++k) {
            float w0 = Ws[cl][k], w1 = Ws[cl+1][k];
            float h0 = Hs[k][pl], h1 = Hs[k][pl+1];
            acc[0][0] += w0*h0; acc[0][1] += w0*h1;
            acc[1][0] += w1*h0; acc[1][1] += w1*h1;
        }
        __syncthreads();
    }
    #pragma unroll
    for (int i = 0; i < 2; ++i)
        #pragma unroll
        for (int j = 0; j < 2; ++j) {
            int cc = c0 + cl + i, p = p0 + pl + j;
            if (p < PP) Y[((size_t)b * PP + p) * CC + cc] = acc[i][j] + 4.0f * b_out[cc];
        }
}

// ---------------------------------------------------------------------------
// softmax over channels -> out[b][c][p]
// ---------------------------------------------------------------------------
__global__ __launch_bounds__(256) void softmax_out(
    const float* __restrict__ Y, float* __restrict__ out) {
    int wave = threadIdx.x >> 6, lane = threadIdx.x & 63;
    int idx = blockIdx.x * 4 + wave;
    if (idx >= BB * PP) return;
    int b = idx / PP, p = idx % PP;
    const float* y = Y + ((size_t)b * PP + p) * CC;
    float v[8];
    float mx = -3.4e38f;
    #pragma unroll
    for (int j = 0; j < 8; ++j) { v[j] = y[lane + 64*j]; mx = fmaxf(mx, v[j]); }
    #pragma unroll
    for (int off = 32; off; off >>= 1) mx = fmaxf(mx, __shfl_xor(mx, off, 64));
    float sum = 0.f;
    #pragma unroll
    for (int j = 0; j < 8; ++j) { v[j] = expf(v[j] - mx); sum += v[j]; }
    #pragma unroll
    for (int off = 32; off; off >>= 1) sum += __shfl_xor(sum, off, 64);
    float r = 1.0f / sum;
    #pragma unroll
    for (int j = 0; j < 8; ++j)
        out[((size_t)b * CC + lane + 64*j) * PP + p] = v[j] * r;
}

// ---------------------------------------------------------------------------
extern "C" void kernel_launch(void* const* d_in, const int* in_sizes, int n_in,
                              void* d_out, int out_size, void* d_ws, size_t ws_size,
                              hipStream_t stream) {
    const float* X     = (const float*)d_in[0];
    const float* Wx    = (const float*)d_in[1];
    const float* Wh    = (const float*)d_in[2];
    const float* b_in  = (const float*)d_in[3];
    const float* Wo    = (const float*)d_in[4];
    const float* b_out = (const float*)d_in[5];
    float* out = (float*)d_out;

    float* ws     = (float*)d_ws;
    float* WhT    = ws;                     // 262144
    float* A      = WhT    + 262144;        // 200704
    float* E      = A      + 200704;        // 802816  [s][cell][c] = exp(U)
    float* h_bulk = E      + 802816;        // 802816  [cell][s][c]
    float* h_t    = h_bulk + 802816;        // 802816  [cell][s][c] full h
    float* TLN    = h_t    + 802816;        // 802816  [cell][s][c] tail from North
    float* TLW    = TLN    + 802816;        // 802816  [cell][s][c] tail from West
    float* Y      = TLW    + 802816;        // 200704
    unsigned char* uflag = (unsigned char*)(Y + 200704);   // PP*64 B
    unsigned char* hflag = uflag + PP * 64;                // PP*64 B
    float* dsAcc = (float*)(hflag + PP * 64);              // PP*16: [cell][N|W]

    hipLaunchKernelGGL(prep, dim3(481), dim3(256), 0, stream,
                       Wx, X, b_in, Wh, A, WhT, (unsigned*)uflag);
    hipLaunchKernelGGL(rnn_dataflow, dim3(NWORK + PP), dim3(512), 0, stream,
                       A, WhT, E, h_bulk, h_t, TLN, TLW, dsAcc, uflag, hflag);
    hipLaunchKernelGGL(gemm_y, dim3(16, 7, 2), dim3(256), 0, stream, Wo, h_t, b_out, Y);
    hipLaunchKernelGGL(softmax_out, dim3(98), dim3(256), 0, stream, Y, out);
}

// Round 7
// 349.907 us; speedup vs baseline: 1.5398x; 1.0104x over previous
//
#include <hip/hip_runtime.h>
#include <hip/hip_bf16.h>

#define BB 2
#define CC 512
#define HH 14
#define WW 14
#define PP 196
#define NSEQ 8
#define NSLICE 8                 // worker WGs per row (64 ch each)
#define NWORK (14 * NSLICE)      // 112
#define FW 16                    // dwords per flag/ds line (64B)
#define NZERO (3 * PP * FW)      // uflag + hflag + dsAcc (all zeroed)
#define ALL8 0x0101010101010101ull

// flags: uflag[cell*64 + w] = 1 byte per slice publish (8 bytes == E/TL/ds ready)
//        hflag[cell*64 + s] = 1 byte per bulk-wave publish (8 bytes == h_bulk ready)

// ---------------------------------------------------------------------------
// prep: gemm_a (224 WGs) + transpose_wh (256 WGs) + flag/dsAcc zero (1 WG)
// ---------------------------------------------------------------------------
__global__ __launch_bounds__(256) void prep(
    const float* __restrict__ Wx, const float* __restrict__ X,
    const float* __restrict__ b_in, const float* __restrict__ Wh,
    float* __restrict__ A, float* __restrict__ WhT,
    unsigned* __restrict__ cnts /* uflag, hflag, dsAcc contiguous */) {
    __shared__ float Ws[32][33], Xs[32][33];
    int bid = blockIdx.x;
    int t = threadIdx.x;
    if (bid < 224) {
        int z = bid / 112, rem = bid % 112;
        int c0 = (rem % 16) * 32, p0 = (rem / 16) * 32;
        int tx = t % 32, ty = t / 32;
        int pl = (t % 16) * 2, cl = (t / 16) * 2;
        float acc[2][2] = {{0.f,0.f},{0.f,0.f}};
        for (int k0 = 0; k0 < CC; k0 += 32) {
            #pragma unroll
            for (int r = 0; r < 4; ++r)
                Ws[ty + 8*r][tx] = Wx[(size_t)(c0 + ty + 8*r) * CC + k0 + tx];
            #pragma unroll
            for (int r = 0; r < 4; ++r) {
                int p = p0 + tx, k = k0 + ty + 8*r;
                Xs[ty + 8*r][tx] = (p < PP) ? X[((size_t)z * CC + k) * PP + p] : 0.f;
            }
            __syncthreads();
            #pragma unroll
            for (int k = 0; k < 32; ++k) {
                float w0 = Ws[cl][k], w1 = Ws[cl+1][k];
                float x0 = Xs[k][pl], x1 = Xs[k][pl+1];
                acc[0][0] += w0*x0; acc[0][1] += w0*x1;
                acc[1][0] += w1*x0; acc[1][1] += w1*x1;
            }
            __syncthreads();
        }
        #pragma unroll
        for (int i = 0; i < 2; ++i)
            #pragma unroll
            for (int j = 0; j < 2; ++j) {
                int c = c0 + cl + i, p = p0 + pl + j;
                if (p < PP) A[((size_t)z * PP + p) * CC + c] = acc[i][j] + b_in[c];
            }
    } else if (bid < 480) {
        int tid = bid - 224;
        int c0 = (tid % 16) * 32, k0 = (tid / 16) * 32;
        int tx = t % 32, ty = t / 32;
        #pragma unroll
        for (int r = 0; r < 4; ++r)
            Ws[ty + 8*r][tx] = Wh[(size_t)(c0 + ty + 8*r) * CC + k0 + tx];
        __syncthreads();
        #pragma unroll
        for (int r = 0; r < 4; ++r)
            WhT[(size_t)(k0 + ty + 8*r) * CC + c0 + tx] = Ws[tx][ty + 8*r];
    } else {
        for (int i = t; i < NZERO; i += 256) cnts[i] = 0u;
    }
}

// ---------------------------------------------------------------------------
// sync primitives
// ---------------------------------------------------------------------------
__device__ __forceinline__ unsigned long long flag8_ld(const unsigned char* f) {
    return __hip_atomic_load((const unsigned long long*)f, __ATOMIC_RELAXED,
                             __HIP_MEMORY_SCOPE_AGENT);
}
__device__ __forceinline__ void flag_st(unsigned char* f) {
    __hip_atomic_store(f, (unsigned char)1, __ATOMIC_RELAXED,
                       __HIP_MEMORY_SCOPE_AGENT);
}
__device__ __forceinline__ float ldf_agent(const float* p) {
    return __hip_atomic_load(p, __ATOMIC_RELAXED, __HIP_MEMORY_SCOPE_AGENT);
}
__device__ __forceinline__ void store_wt(float* p, float v) {
    __hip_atomic_store(p, v, __ATOMIC_RELAXED, __HIP_MEMORY_SCOPE_AGENT);
}

// one window pixel for 8 channels (this wave's seq); E = exp(U) input
__device__ __forceinline__ void pix(const float4 E0, const float4 E1,
                                    const float* ar, const float* er, float* hacc) {
    float ee[8] = {E0.x,E0.y,E0.z,E0.w,E1.x,E1.y,E1.z,E1.w};
    float ds = 0.f, tl[8];
    #pragma unroll
    for (int j = 0; j < 8; ++j) {
        float sv = ar[j] + __logf(ee[j]);
        float pv = er[j] * ee[j];
        ds += fmaxf(pv, 1.0f);
        tl[j] = fmaxf(sv, 0.0f) * pv;
    }
    #pragma unroll
    for (int off = 32; off; off >>= 1) ds += __shfl_xor(ds, off, 64);
    float rd = 1.0f / ds;
    #pragma unroll
    for (int j = 0; j < 8; ++j) hacc[j] += tl[j] * rd;
}

// process n pixels at rowp + y*CC, 4-deep pipelined plain loads
__device__ __forceinline__ void proc_row(const float* __restrict__ rowp, int n,
                                         const float* ar, const float* er, float* hacc) {
    float4 cur[4][2];
    int y = 0, curn = (n < 4) ? n : 4;
    #pragma unroll
    for (int i = 0; i < 4; ++i) if (i < curn) {
        cur[i][0] = *(const float4*)(rowp + (size_t)i * CC);
        cur[i][1] = *(const float4*)(rowp + (size_t)i * CC + 256);
    }
    while (true) {
        int yn = y + curn;
        int rem = n - yn;
        int nextn = (rem < 4) ? rem : 4;
        float4 nxt[4][2];
        #pragma unroll
        for (int i = 0; i < 4; ++i) if (i < nextn) {
            nxt[i][0] = *(const float4*)(rowp + (size_t)(yn + i) * CC);
            nxt[i][1] = *(const float4*)(rowp + (size_t)(yn + i) * CC + 256);
        }
        #pragma unroll
        for (int i = 0; i < 4; ++i) if (i < curn)
            pix(cur[i][0], cur[i][1], ar, er, hacc);
        if (nextn <= 0) break;
        #pragma unroll
        for (int i = 0; i < 4; ++i) if (i < nextn) {
            cur[i][0] = nxt[i][0]; cur[i][1] = nxt[i][1];
        }
        curn = nextn; y = yn;
    }
}

// ---------------------------------------------------------------------------
// One kernel, two roles:
//   blockIdx 0..111   : row workers (row=bid>>3, 64-ch slice).
//     Round 7: extend the uniform-prefetch (pf) verdict to the NORTH dep.
//     Steady-state wavefront: N data for cell+1 -- TLN + dsAcc N-half,
//     published by row px-1 at (px-1,py+1) -- is flagged at ~the same time
//     we publish cell py. At our publish, t==0 also checks uflag(N(cell+1));
//     on hit, prefetch TLN/dsN into loop-carried regs (tnr/dsNr) right after
//     the drain barrier. Next cell then polls W ONLY and the load leg halves.
//     All verdicts are workgroup-uniform (round-6 LDS-broadcast pattern).
//   blockIdx 112..307 : per-cell bulk WGs, chunked rows, byte-flag gates.
// ---------------------------------------------------------------------------
__global__ __launch_bounds__(512, 2) void rnn_dataflow(
    const float* __restrict__ A, const float* __restrict__ WhT,
    float* __restrict__ E, float* __restrict__ h_bulk,
    float* __restrict__ h_t, float* __restrict__ TLN,
    float* __restrict__ TLW, float* __restrict__ dsAcc,
    unsigned char* __restrict__ uflag, unsigned char* __restrict__ hflag) {
    __shared__ __align__(16) float hT8[CC * 8];   // full h [k][s], stride 8
    __shared__ __align__(16) float up[8 * 576];   // matvec partials [wave][c*9+s]
    __shared__ unsigned mbox;                     // bulk WG: ready-chunks bitmap
    __shared__ unsigned pf;                       // worker: uniform prefetch verdict
    int bid = blockIdx.x;
    int t = threadIdx.x;
    int lane = t & 63, wv = t >> 6;

    if (bid < NWORK) {
        // ================= row worker =================
        int px = bid >> 3, w = bid & 7;
        int ch = w * 64 + lane;                   // this thread's publish channel
        int m = wv >> 1, b = wv & 1;              // seq decode (s = wv)
        float wreg2[64];                          // WhT[64wv+kk][ch]
        #pragma unroll
        for (int kk = 0; kk < 64; ++kk)
            wreg2[kk] = WhT[(size_t)(wv * 64 + kk) * CC + ch];
        __builtin_amdgcn_s_setprio(1);

        float hb[8];
        float tnr[8], dsNr[8];    // loop-carried N-tail prefetch
        bool hb_ok = false;       // hb[] prefetched for upcoming cell? (uniform)
        bool n_ok  = false;       // tnr/dsNr prefetched? (uniform)

        for (int py = 0; py < WW; ++py) {
            int cell = px * WW + py;
            int cellN = cell - WW, cellW = cell - 1;

            // prefetch consumer-cell a values (overlaps the polls)
            float aSr = 0.f, aWr = 0.f;
            if (px < HH - 1) {
                int fi = (m & 2) ? (HH - 2 - px) : (px + 1);
                int fj = (m & 1) ? (WW - 1 - py) : py;
                aSr = A[((size_t)b * PP + fi * WW + fj) * CC + ch];
            }
            if (py < WW - 1) {
                int fi = (m & 2) ? (HH - 1 - px) : px;
                int fj = (m & 1) ? (WW - 2 - py) : (py + 1);
                aWr = A[((size_t)b * PP + fi * WW + fj) * CC + ch];
            }

            // phase 1 (fallback only, hb_ok uniform): observe + load h_bulk
            if (!hb_ok) {
                if (wv == 0 && lane == 0)
                    while (flag8_ld(hflag + (size_t)cell * 64) != ALL8)
                        __builtin_amdgcn_s_sleep(1);
                __syncthreads();
                asm volatile("" ::: "memory");
                #pragma unroll
                for (int s = 0; s < 8; ++s)
                    hb[s] = h_bulk[((size_t)cell * NSEQ + s) * CC + t];
            }

            // phase 2: W (and N only if not prefetched) ready?
            if (wv == 0) {
                while (true) {
                    unsigned ok = 1u;
                    if (lane == 0)      { if (py > 0) ok = (flag8_ld(uflag + (size_t)cellW * 64) == ALL8); }
                    else if (lane == 1) { if (px > 0 && !n_ok) ok = (flag8_ld(uflag + (size_t)cellN * 64) == ALL8); }
                    if (__ballot(ok != 0u) == ~0ull) break;
                    __builtin_amdgcn_s_sleep(1);
                }
            }
            __syncthreads();
            asm volatile("" ::: "memory");

            // load leg: N part only on prefetch miss; W always (flag race)
            if (px > 0) {
                if (!n_ok) {
                    #pragma unroll
                    for (int i = 0; i < 8; ++i)
                        dsNr[i] = ldf_agent(&dsAcc[(size_t)cell * 16 + i]);
                    #pragma unroll
                    for (int s = 0; s < 8; ++s)
                        tnr[s] = ldf_agent(&TLN[((size_t)cell * NSEQ + s) * CC + t]);
                }
                #pragma unroll
                for (int s = 0; s < 8; ++s)
                    hb[s] += tnr[s] * __builtin_amdgcn_rcpf(dsNr[s]);
            }
            if (py > 0) {
                float dsw[8], tw[8];
                #pragma unroll
                for (int i = 0; i < 8; ++i)
                    dsw[i] = ldf_agent(&dsAcc[(size_t)cell * 16 + 8 + i]);
                #pragma unroll
                for (int s = 0; s < 8; ++s)
                    tw[s] = ldf_agent(&TLW[((size_t)cell * NSEQ + s) * CC + t]);
                #pragma unroll
                for (int s = 0; s < 8; ++s)
                    hb[s] += tw[s] * __builtin_amdgcn_rcpf(dsw[s]);
            }
            if (wv == w) {   // h_t: this slice's own 64-ch stripe only
                #pragma unroll
                for (int s = 0; s < 8; ++s)
                    h_t[((size_t)cell * NSEQ + s) * CC + t] = hb[s];
            }
            *(float4*)&hT8[t * 8]     = make_float4(hb[0], hb[1], hb[2], hb[3]);
            *(float4*)&hT8[t * 8 + 4] = make_float4(hb[4], hb[5], hb[6], hb[7]);
            // no barrier: wave wv's matvec reads exactly its own threads' stripe
            if (cell == PP - 1) break;           // (13,13): no U consumer

            // matvec: wave wv owns k in [64wv, 64wv+64); lane owns channel.
            float acc[8] = {0.f,0.f,0.f,0.f,0.f,0.f,0.f,0.f};
            const float* hp = hT8 + (wv << 9);
            #pragma unroll
            for (int kk = 0; kk < 64; ++kk) {
                float4 h0 = *(const float4*)(hp + kk * 8);
                float4 h1 = *(const float4*)(hp + kk * 8 + 4);
                float wvv = wreg2[kk];
                acc[0] += wvv * h0.x; acc[1] += wvv * h0.y;
                acc[2] += wvv * h0.z; acc[3] += wvv * h0.w;
                acc[4] += wvv * h1.x; acc[5] += wvv * h1.y;
                acc[6] += wvv * h1.z; acc[7] += wvv * h1.w;
            }
            #pragma unroll
            for (int s = 0; s < 8; ++s)
                up[wv * 576 + lane * 9 + s] = acc[s];   // full overwrite, no zeroing
            __syncthreads();

            // publish: U, E = exp(U), consumer tails + denominator partials
            {
                float U = up[lane * 9 + wv];
                #pragma unroll
                for (int w2 = 1; w2 < 8; ++w2) U += up[w2 * 576 + lane * 9 + wv];
                float Ev = __expf(U);
                store_wt(&E[((size_t)wv * PP + cell) * CC + ch], Ev);
                float pdS = 0.f, pdW = 0.f;
                if (px < HH - 1) {
                    float pv = __expf(aSr) * Ev;
                    store_wt(&TLN[((size_t)(cell + WW) * NSEQ + wv) * CC + ch],
                             fmaxf(aSr + U, 0.f) * pv);
                    pdS = fmaxf(pv, 1.f);
                }
                if (py < WW - 1) {
                    float pv = __expf(aWr) * Ev;
                    store_wt(&TLW[((size_t)(cell + 1) * NSEQ + wv) * CC + ch],
                             fmaxf(aWr + U, 0.f) * pv);
                    pdW = fmaxf(pv, 1.f);
                }
                #pragma unroll
                for (int off = 32; off; off >>= 1) {
                    pdS += __shfl_xor(pdS, off, 64);
                    pdW += __shfl_xor(pdW, off, 64);
                }
                if (lane == 0) {
                    if (px < HH - 1)
                        unsafeAtomicAdd(&dsAcc[(size_t)(cell + WW) * 16 + wv], pdS);
                    if (py < WW - 1)
                        unsafeAtomicAdd(&dsAcc[(size_t)(cell + 1) * 16 + 8 + wv], pdW);
                }
            }

            // uniform prefetch verdicts for cell+1 (ONE reader, LDS broadcast):
            //   bit0: h_bulk(cell+1) ready   bit1: N(cell+1) publishes ready
            if (t == 0) {
                unsigned v = 0u;
                if (py + 1 < WW) {
                    if (flag8_ld(hflag + (size_t)(cell + 1) * 64) == ALL8) v |= 1u;
                    if (px > 0 &&
                        flag8_ld(uflag + (size_t)(cellN + 1) * 64) == ALL8) v |= 2u;
                }
                pf = v;
            }

            __syncthreads();     // drain: stores/atomics acked; pf visible
            if (t == 0) flag_st(uflag + (size_t)cell * 64 + w);   // byte, no RMW

            hb_ok = false; n_ok = false;
            if (py + 1 < WW) {
                unsigned v = pf;
                if (v & 1u) {
                    #pragma unroll
                    for (int s = 0; s < 8; ++s)
                        hb[s] = h_bulk[((size_t)(cell + 1) * NSEQ + s) * CC + t];
                    hb_ok = true;
                }
                if (v & 2u) {    // px > 0 guaranteed by verdict
                    #pragma unroll
                    for (int i = 0; i < 8; ++i)
                        dsNr[i] = ldf_agent(&dsAcc[(size_t)(cell + 1) * 16 + i]);
                    #pragma unroll
                    for (int s = 0; s < 8; ++s)
                        tnr[s] = ldf_agent(&TLN[((size_t)(cell + 1) * NSEQ + s) * CC + t]);
                    n_ok = true;
                }
            }
        }
    } else {
        // ================= bulk window WG (chunked rows), off-path ==========
        int cell = bid - NWORK;
        int px = cell / WW, py = cell % WW;
        int s = wv, m = s >> 1, b = s & 1;
        int fi = (m & 2) ? (HH-1-px) : px;
        int fj = (m & 1) ? (WW-1-py) : py;
        int cb = lane * 4;

        if (t == 0) mbox = 0u;
        __syncthreads();          // once, at WG start (long before deps ready)

        const float* acur = A + ((size_t)b * PP + fi * WW + fj) * CC;
        float4 a0 = *(const float4*)(acur + cb);
        float4 a1 = *(const float4*)(acur + cb + 256);
        float ar[8] = {a0.x,a0.y,a0.z,a0.w,a1.x,a1.y,a1.z,a1.w};
        float er[8];
        #pragma unroll
        for (int j = 0; j < 8; ++j) er[j] = __expf(ar[j]);
        float hacc[8] = {0.f,0.f,0.f,0.f,0.f,0.f,0.f,0.f};

        {   // self pixel first (needs no U at all): U=0 -> E=1
            float ds = 0.f, tl[8];
            #pragma unroll
            for (int j = 0; j < 8; ++j) {
                float pv = er[j];
                ds += fmaxf(pv, 1.0f);
                tl[j] = fmaxf(ar[j], 0.0f) * pv;
            }
            #pragma unroll
            for (int off = 32; off; off >>= 1) ds += __shfl_xor(ds, off, 64);
            float rd = 1.0f / ds;
            #pragma unroll
            for (int j = 0; j < 8; ++j) hacc[j] += tl[j] * rd;
        }

        const float* Eb = E + (size_t)s * PP * CC;
        // chunk slots: slot = lane, row x = lane>>1, phase = lane&1.
        // row limit L: x<=px-2 -> py ; x=px-1 -> py-1 ; x=px -> py-2
        //   L<=2 : single chunk [0..L]    gate (x,L)     at slot (2x+0)
        //   L>2  : early [0..L-3]         gate (x,L-3)   at slot (2x+0)
        //          late  [L-2..L] (3 px)  gate (x,L)     at slot (2x+1)
        int sx = lane >> 1, sph = lane & 1;
        int gate = -1;
        if (sx <= px) {
            int L = (sx <= px-2) ? py : ((sx == px-1) ? py-1 : py-2);
            if (L >= 0) {
                if (L <= 2) { if (sph == 0) gate = sx * WW + L; }
                else gate = sx * WW + (sph ? L : (L - 3));
            }
        }
        unsigned pend = (unsigned)__ballot(gate >= 0);

        if (wv == 0) {
            // sole fabric poller: lane l checks its chunk's gate flags (1 load)
            unsigned done = 0u;
            while (pend) {
                bool rdy = true;
                if (gate >= 0 && ((pend >> lane) & 1u))
                    rdy = (flag8_ld(uflag + (size_t)gate * 64) == ALL8);
                unsigned newly = pend & (unsigned)__ballot(rdy);
                if (!newly) { __builtin_amdgcn_s_sleep(2); continue; }
                done |= newly;
                __hip_atomic_store(&mbox, done, __ATOMIC_RELAXED,
                                   __HIP_MEMORY_SCOPE_WORKGROUP);
                asm volatile("" ::: "memory");
                unsigned go = newly;
                while (go) {
                    int sl = __ffs(go) - 1; go &= go - 1;
                    int xx = sl >> 1;
                    int L = (xx <= px-2) ? py : ((xx == px-1) ? py-1 : py-2);
                    int yy0 = 0, yy1 = L;
                    if (L > 2) { if (sl & 1) yy0 = L - 2; else yy1 = L - 3; }
                    proc_row(Eb + (size_t)(xx * WW + yy0) * CC + cb,
                             yy1 - yy0 + 1, ar, er, hacc);
                }
                pend &= ~newly;
            }
        } else {
            while (pend) {
                unsigned d = __hip_atomic_load(&mbox, __ATOMIC_RELAXED,
                                               __HIP_MEMORY_SCOPE_WORKGROUP);
                unsigned newly = d & pend;
                if (!newly) { __builtin_amdgcn_s_sleep(2); continue; }
                asm volatile("" ::: "memory");
                unsigned go = newly;
                while (go) {
                    int sl = __ffs(go) - 1; go &= go - 1;
                    int xx = sl >> 1;
                    int L = (xx <= px-2) ? py : ((xx == px-1) ? py-1 : py-2);
                    int yy0 = 0, yy1 = L;
                    if (L > 2) { if (sl & 1) yy0 = L - 2; else yy1 = L - 3; }
                    proc_row(Eb + (size_t)(xx * WW + yy0) * CC + cb,
                             yy1 - yy0 + 1, ar, er, hacc);
                }
                pend &= ~newly;
            }
        }

        // per-wave publish h_bulk: contiguous WT stores + drain + byte flag
        float* hp = h_bulk + ((size_t)cell * NSEQ + s) * CC;
        #pragma unroll
        for (int j = 0; j < 4; ++j) {
            store_wt(hp + cb + j,       hacc[j]);
            store_wt(hp + cb + 256 + j, hacc[4 + j]);
        }
        __builtin_amdgcn_s_waitcnt(0);
        asm volatile("" ::: "memory");
        if (lane == 0) flag_st(hflag + (size_t)cell * 64 + s);
    }
}

// ---------------------------------------------------------------------------
// gemm_y: Y[b][p][c] = sum_k Wo[c][k] * (sum_m h_t[p][2m+b][k]) + 4*b_out[c]
// ---------------------------------------------------------------------------
__global__ __launch_bounds__(256) void gemm_y(
    const float* __restrict__ Wo, const float* __restrict__ h_t,
    const float* __restrict__ b_out, float* __restrict__ Y) {
    __shared__ float Ws[32][33], Hs[32][33];
    int b  = blockIdx.z;
    int c0 = blockIdx.x * 32, p0 = blockIdx.y * 32;
    int t  = threadIdx.x;
    int tx = t % 32, ty = t / 32;
    int pl = (t % 16) * 2, cl = (t / 16) * 2;
    float acc[2][2] = {{0.f,0.f},{0.f,0.f}};
    for (int k0 = 0; k0 < CC; k0 += 32) {
        #pragma unroll
        for (int r = 0; r < 4; ++r)
            Ws[ty + 8*r][tx] = Wo[(size_t)(c0 + ty + 8*r) * CC + k0 + tx];
        #pragma unroll
        for (int r = 0; r < 4; ++r) {
            int p = p0 + ty + 8*r;
            float v = 0.f;
            if (p < PP) {
                size_t base = (size_t)p * NSEQ * CC + k0 + tx;
                v = h_t[base + (size_t)(0 + b) * CC]
                  + h_t[base + (size_t)(2 + b) * CC]
                  + h_t[base + (size_t)(4 + b) * CC]
                  + h_t[base + (size_t)(6 + b) * CC];
            }
            Hs[tx][ty + 8*r] = v;
        }
        __syncthreads();
        #pragma unroll
        for (int k = 0; k < 32; ++k) {
            float w0 = Ws[cl][k], w1 = Ws[cl+1][k];
            float h0 = Hs[k][pl], h1 = Hs[k][pl+1];
            acc[0][0] += w0*h0; acc[0][1] += w0*h1;
            acc[1][0] += w1*h0; acc[1][1] += w1*h1;
        }
        __syncthreads();
    }
    #pragma unroll
    for (int i = 0; i < 2; ++i)
        #pragma unroll
        for (int j = 0; j < 2; ++j) {
            int cc = c0 + cl + i, p = p0 + pl + j;
            if (p < PP) Y[((size_t)b * PP + p) * CC + cc] = acc[i][j] + 4.0f * b_out[cc];
        }
}

// ---------------------------------------------------------------------------
// softmax over channels -> out[b][c][p]
// ---------------------------------------------------------------------------
__global__ __launch_bounds__(256) void softmax_out(
    const float* __restrict__ Y, float* __restrict__ out) {
    int wave = threadIdx.x >> 6, lane = threadIdx.x & 63;
    int idx = blockIdx.x * 4 + wave;
    if (idx >= BB * PP) return;
    int b = idx / PP, p = idx % PP;
    const float* y = Y + ((size_t)b * PP + p) * CC;
    float v[8];
    float mx = -3.4e38f;
    #pragma unroll
    for (int j = 0; j < 8; ++j) { v[j] = y[lane + 64*j]; mx = fmaxf(mx, v[j]); }
    #pragma unroll
    for (int off = 32; off; off >>= 1) mx = fmaxf(mx, __shfl_xor(mx, off, 64));
    float sum = 0.f;
    #pragma unroll
    for (int j = 0; j < 8; ++j) { v[j] = expf(v[j] - mx); sum += v[j]; }
    #pragma unroll
    for (int off = 32; off; off >>= 1) sum += __shfl_xor(sum, off, 64);
    float r = 1.0f / sum;
    #pragma unroll
    for (int j = 0; j < 8; ++j)
        out[((size_t)b * CC + lane + 64*j) * PP + p] = v[j] * r;
}

// ---------------------------------------------------------------------------
extern "C" void kernel_launch(void* const* d_in, const int* in_sizes, int n_in,
                              void* d_out, int out_size, void* d_ws, size_t ws_size,
                              hipStream_t stream) {
    const float* X     = (const float*)d_in[0];
    const float* Wx    = (const float*)d_in[1];
    const float* Wh    = (const float*)d_in[2];
    const float* b_in  = (const float*)d_in[3];
    const float* Wo    = (const float*)d_in[4];
    const float* b_out = (const float*)d_in[5];
    float* out = (float*)d_out;

    float* ws     = (float*)d_ws;
    float* WhT    = ws;                     // 262144
    float* A      = WhT    + 262144;        // 200704
    float* E      = A      + 200704;        // 802816  [s][cell][c] = exp(U)
    float* h_bulk = E      + 802816;        // 802816  [cell][s][c]
    float* h_t    = h_bulk + 802816;        // 802816  [cell][s][c] full h
    float* TLN    = h_t    + 802816;        // 802816  [cell][s][c] tail from North
    float* TLW    = TLN    + 802816;        // 802816  [cell][s][c] tail from West
    float* Y      = TLW    + 802816;        // 200704
    unsigned char* uflag = (unsigned char*)(Y + 200704);   // PP*64 B
    unsigned char* hflag = uflag + PP * 64;                // PP*64 B
    float* dsAcc = (float*)(hflag + PP * 64);              // PP*16: [cell][N|W]

    hipLaunchKernelGGL(prep, dim3(481), dim3(256), 0, stream,
                       Wx, X, b_in, Wh, A, WhT, (unsigned*)uflag);
    hipLaunchKernelGGL(rnn_dataflow, dim3(NWORK + PP), dim3(512), 0, stream,
                       A, WhT, E, h_bulk, h_t, TLN, TLW, dsAcc, uflag, hflag);
    hipLaunchKernelGGL(gemm_y, dim3(16, 7, 2), dim3(256), 0, stream, Wo, h_t, b_out, Y);
    hipLaunchKernelGGL(softmax_out, dim3(98), dim3(256), 0, stream, Y, out);
}